// Round 11
// baseline (4296.975 us; speedup 1.0000x reference)
//
#include <hip/hip_runtime.h>
#include <hip/hip_bf16.h>
#include <cstdint>
#include <cstddef>

// Problem constants (fixed by reference)
#define B_    8
#define T_    256
#define D_    512
#define W_    32
#define L_    4
#define A_    6
#define H_    8
#define DH_   64
#define DHP   65                 // padded LDS row (attn bank-conflict fix, R5)
#define NWIN  (B_*T_)            // 2048 windows
#define NTOK  (NWIN*W_)          // 65536 token rows

typedef __hip_bfloat16 bf16;
using bf16x8 = __attribute__((ext_vector_type(8))) short;  // MFMA A/B frag (4 VGPR)
using f32x4  = __attribute__((ext_vector_type(4))) float;  // MFMA C/D frag

// ---- memory plan (bytes): bf16-only residual stream ----------------------
#define XB_BYTES  ((size_t)NTOK * D_ * 2)     // 64 MiB bf16 residual master
#define WQ_ELEMS  ((size_t)L_ * 3*D_*D_)
#define WO_ELEMS  ((size_t)L_ * D_*D_)
#define W1_ELEMS  ((size_t)L_ * 4*D_*D_)
#define W2_ELEMS  ((size_t)L_ * 4*D_*D_)
#define WB_BYTES  ((WQ_ELEMS + WO_ELEMS + W1_ELEMS + W2_ELEMS) * 2)
#define SCR_BYTES ((size_t)NTOK * 2048 * 2)   // qkv(1536)+ctx(512) / h(2048)
#define TOTAL_BYTES (XB_BYTES + WB_BYTES + SCR_BYTES)

static char* g_fallback = nullptr;
__attribute__((constructor)) static void alloc_fallback() {
    (void)hipMalloc((void**)&g_fallback, TOTAL_BYTES);
}

// ---- async global->LDS (16B per lane; LDS dest = wave base + lane*16) -----
typedef __attribute__((address_space(3))) uint8_t* as3p;
typedef const __attribute__((address_space(1))) uint8_t* as1p;
__device__ __forceinline__ void gload_lds16(const void* g, void* l) {
    __builtin_amdgcn_global_load_lds((as1p)(const uint8_t*)g,
                                     (as3p)(uint32_t)(uintptr_t)l, 16, 0, 0);
}

__device__ __forceinline__ float bf2f(short s) {
    return __uint_as_float(((uint32_t)(uint16_t)s) << 16);
}

// ---------------------------------------------------------------------------
// weight convert fp32 -> bf16 (4 elems/thread)
// ---------------------------------------------------------------------------
__global__ __launch_bounds__(256) void cvt_kernel(
    const float* __restrict__ w, bf16* __restrict__ o, int n4)
{
    int i = blockIdx.x * 256 + threadIdx.x;
    if (i >= n4) return;
    float4 f = ((const float4*)w)[i];
    bf16* d = o + (size_t)i * 4;
    d[0] = __float2bfloat16(f.x);
    d[1] = __float2bfloat16(f.y);
    d[2] = __float2bfloat16(f.z);
    d[3] = __float2bfloat16(f.w);
}

// ---------------------------------------------------------------------------
// build_x: xb[n*32+w,:] = bf16(feats[b, max(t+w-31,0),:] + pos[w,:])
// ---------------------------------------------------------------------------
__global__ __launch_bounds__(256) void build_x_kernel(
    const float* __restrict__ feats,
    const float* __restrict__ pos,
    bf16* __restrict__ xb)
{
    int gid   = blockIdx.x * 256 + threadIdx.x;   // over NTOK * (D/4)
    int token = gid >> 7;
    int c4    = (gid & 127) * 4;
    int w     = token & (W_-1);
    int n     = token >> 5;
    int t     = n & (T_-1);
    int b     = n >> 8;
    int frame = t + w - (W_-1); if (frame < 0) frame = 0;
    const float4 f = *(const float4*)(feats + ((size_t)(b*T_ + frame)*D_ + c4));
    const float4 p = *(const float4*)(pos   + ((size_t)w*D_ + c4));
    bf16* d = xb + (size_t)token*D_ + c4;
    d[0] = __float2bfloat16(f.x + p.x);
    d[1] = __float2bfloat16(f.y + p.y);
    d[2] = __float2bfloat16(f.z + p.z);
    d[3] = __float2bfloat16(f.w + p.w);
}

// ---------------------------------------------------------------------------
// bf16 MFMA GEMM (R8 version, BK=32):
// Cb = bf16(A(MxK) @ Bt(NxK)^T + bias [relu])
// 128x128 tile, 4 waves, wave 64x64 (4x4 of 16x16x32 MFMA).
// 1-D grid + XCD remap (R7: same-A-stripe blocks share one XCD L2).
// ---------------------------------------------------------------------------
template<bool RELU>
__global__ __launch_bounds__(256) void gemm_bf16(
    const bf16* __restrict__ A,
    const bf16* __restrict__ Bt,
    const float* __restrict__ bias,
    bf16* __restrict__ Cb,
    int M, int N, int K)
{
    __shared__ bf16 As[128*32];   // [row][k] row-major, 64B rows
    __shared__ bf16 Bs[128*32];

    const int tid  = threadIdx.x;
    const int lane = tid & 63;
    const int wv   = tid >> 6;

    // XCD-aware block remap (gridM % 8 == 0)
    const int gridN = N >> 7;
    const int bid   = blockIdx.x;
    const int q_    = bid >> 3;
    const int n0    = (q_ % gridN) << 7;
    const int m0    = (((q_ / gridN) * 8) + (bid & 7)) << 7;

    const int wm   = (wv >> 1) * 64;
    const int wn   = (wv & 1) * 64;

    f32x4 acc[4][4] = {};

    const int   srow  = wv*16 + (lane >> 2);
    const int   skoff = (lane & 3) * 8;
    const bf16* ga0 = A  + (size_t)(m0 + srow)      * K + skoff;
    const bf16* ga1 = A  + (size_t)(m0 + 64 + srow) * K + skoff;
    const bf16* gb0 = Bt + (size_t)(n0 + srow)      * K + skoff;
    const bf16* gb1 = Bt + (size_t)(n0 + 64 + srow) * K + skoff;
    char* lAs = (char*)As;
    char* lBs = (char*)Bs;
    const int l0 = wv*1024 + lane*16;

    const int fr = lane & 15;
    const int fq = (lane >> 4) * 16;

    for (int k0 = 0; k0 < K; k0 += 32) {
        gload_lds16(ga0 + k0, lAs + l0);
        gload_lds16(ga1 + k0, lAs + l0 + 4096);
        gload_lds16(gb0 + k0, lBs + l0);
        gload_lds16(gb1 + k0, lBs + l0 + 4096);
        __syncthreads();

        bf16x8 av[4], bv[4];
#pragma unroll
        for (int i = 0; i < 4; ++i) {
            av[i] = *(const bf16x8*)(lAs + (wm + i*16 + fr)*64 + fq);
            bv[i] = *(const bf16x8*)(lBs + (wn + i*16 + fr)*64 + fq);
        }
#pragma unroll
        for (int i = 0; i < 4; ++i)
#pragma unroll
            for (int j = 0; j < 4; ++j)
                acc[i][j] = __builtin_amdgcn_mfma_f32_16x16x32_bf16(
                    av[i], bv[j], acc[i][j], 0, 0, 0);
        __syncthreads();
    }

    // epilogue: C/D layout col=lane&15, row=(lane>>4)*4+reg
    const int er = (lane >> 4) * 4;
    const int ec = lane & 15;
#pragma unroll
    for (int i = 0; i < 4; ++i) {
#pragma unroll
        for (int j = 0; j < 4; ++j) {
            const int ncol = n0 + wn + j*16 + ec;
            const float bv_ = bias[ncol];
#pragma unroll
            for (int r = 0; r < 4; ++r) {
                const int mrow = m0 + wm + i*16 + er + r;
                float v = acc[i][j][r] + bv_;
                if (RELU) v = fmaxf(v, 0.f);
                Cb[(size_t)mrow * N + ncol] = __float2bfloat16(v);
            }
        }
    }
}

// ---------------------------------------------------------------------------
// Fused residual GEMM + LayerNorm — R11: BARRIER-FREE K-loop.
//   y = xres + A @ Bt^T + bias;  xout = LN(y) * g + b      (N fixed = 512)
// 32 rows x 512 cols per block. Wave wv covers cols [wv*128, wv*128+128):
// B column-groups are wave-DISJOINT, so each wave stages its OWN B-slice
// (8 KB) + its own copy of the 2 KB A-tile into wave-private LDS and syncs
// with a wave-local s_waitcnt(0) instead of __syncthreads. No block barrier
// in the K-loop -> no 4-wave DMA convoy; waves slip and cover each other's
// ~900-cyc HBM drains (R8-R10 showed this kernel latency-bound: MFMA 15%,
// VALU 14%, HBM 9% all idle). Single-buffer safe: ds_reads land in regs
// (lgkm drained before MFMA) before next iter's DMA issues in program order.
// LDS 41 KB -> 3 blocks/CU. Epilogue keeps its single barrier for LN.
// In-place xres==xout safe: each block reads/writes only its own 32 rows.
// ---------------------------------------------------------------------------
__global__ __launch_bounds__(256) void gemm_ln(
    const bf16* __restrict__ A,     // (M x K)
    const bf16* __restrict__ Bt,    // (512 x K)
    const float* __restrict__ bias, // (512)
    const bf16* xres,               // (M x 512), aliases xout
    bf16* xout,
    const float* __restrict__ g,
    const float* __restrict__ b,
    int K)
{
    __shared__ bf16 AsW[4][32*32];   // per-wave A copy, 2 KB each
    __shared__ bf16 BsW[4][128*32];  // per-wave B slice, 8 KB each
    __shared__ float red[4][32][2];  // per-wave LN row partials

    const int tid  = threadIdx.x;
    const int lane = tid & 63;
    const int wv   = tid >> 6;
    const int m0   = (gridDim.x - 1 - blockIdx.x) * 32;   // reversed order
    const int wc   = wv * 128;                            // wave col offset

    f32x4 acc[2][8] = {};

    const int sr = lane >> 2;          // staging row within 16-row group
    const int sc = (lane & 3) * 8;     // staging k-offset (elems)
    char* lA = (char*)AsW[wv];
    char* lB = (char*)BsW[wv];
    const int dst = lane * 16;

    const int fr = lane & 15;
    const int fq = (lane >> 4) * 16;

    for (int k0 = 0; k0 < K; k0 += 32) {
        // A tile: 32 rows x 32 k (2 instr, wave-private copy)
        gload_lds16(A + (size_t)(m0 + sr)      * K + k0 + sc, lA + dst);
        gload_lds16(A + (size_t)(m0 + 16 + sr) * K + k0 + sc, lA + 1024 + dst);
        // B slice: rows wc..wc+128 (8 instr)
#pragma unroll
        for (int jj = 0; jj < 8; ++jj)
            gload_lds16(Bt + (size_t)(wc + jj*16 + sr) * K + k0 + sc,
                        lB + jj*1024 + dst);
        __builtin_amdgcn_s_waitcnt(0);   // wave-local DMA drain (NO barrier)

        bf16x8 av[2], bv[8];
#pragma unroll
        for (int i = 0; i < 2; ++i)
            av[i] = *(const bf16x8*)(lA + (i*16 + fr)*64 + fq);
#pragma unroll
        for (int j = 0; j < 8; ++j)
            bv[j] = *(const bf16x8*)(lB + (j*16 + fr)*64 + fq);
#pragma unroll
        for (int i = 0; i < 2; ++i)
#pragma unroll
            for (int j = 0; j < 8; ++j)
                acc[i][j] = __builtin_amdgcn_mfma_f32_16x16x32_bf16(
                    av[i], bv[j], acc[i][j], 0, 0, 0);
        // no __syncthreads: LDS is wave-private; regs hold data before next DMA
    }

    // ---- epilogue: v = acc + bias + resid; LN over the 512-wide row ----
    const int er = (lane >> 4) * 4;
    const int ec = lane & 15;

    float bias_j[8];
#pragma unroll
    for (int j = 0; j < 8; ++j) bias_j[j] = bias[wc + j*16 + ec];

#pragma unroll
    for (int i = 0; i < 2; ++i) {
#pragma unroll
        for (int r = 0; r < 4; ++r) {
            const int row = i*16 + er + r;
            const bf16* xr = xres + (size_t)(m0 + row) * D_ + wc + ec;
            float s1 = 0.f, s2 = 0.f;
#pragma unroll
            for (int j = 0; j < 8; ++j) {
                float v = acc[i][j][r] + bias_j[j] + bf2f(*(const short*)(xr + j*16));
                acc[i][j][r] = v;
                s1 += v; s2 += v*v;
            }
#pragma unroll
            for (int mask = 1; mask < 16; mask <<= 1) {
                s1 += __shfl_xor(s1, mask, 64);
                s2 += __shfl_xor(s2, mask, 64);
            }
            if (ec == 0) { red[wv][row][0] = s1; red[wv][row][1] = s2; }
        }
    }
    __syncthreads();   // single barrier: cross-wave LN reduction

#pragma unroll
    for (int i = 0; i < 2; ++i) {
#pragma unroll
        for (int r = 0; r < 4; ++r) {
            const int row = i*16 + er + r;
            float t1 = red[0][row][0] + red[1][row][0] + red[2][row][0] + red[3][row][0];
            float t2 = red[0][row][1] + red[1][row][1] + red[2][row][1] + red[3][row][1];
            const float mu  = t1 * (1.f / D_);
            float var = t2 * (1.f / D_) - mu * mu;
            if (var < 0.f) var = 0.f;
            const float rs = rsqrtf(var + 1e-5f);
            bf16* xo = xout + (size_t)(m0 + row) * D_ + wc + ec;
#pragma unroll
            for (int j = 0; j < 8; ++j) {
                const int col = wc + j*16 + ec;
                float o = (acc[i][j][r] - mu) * rs * g[col] + b[col];
                xo[j*16] = __float2bfloat16(o);
            }
        }
    }
}

// ---------------------------------------------------------------------------
// Attention: block per (window, head); bf16 qkv in, bf16 ctx out; fp32 inside.
// LDS rows padded to DHP=65 floats (R5 bank-conflict fix).
// ---------------------------------------------------------------------------
__global__ __launch_bounds__(256) void attn_kernel(
    const bf16* __restrict__ qkv,
    bf16* __restrict__ ctx)
{
    const int n = blockIdx.x;
    const int h = blockIdx.y;
    __shared__ float q[W_][DHP];
    __shared__ float k[W_][DHP];
    __shared__ float v[W_][DHP];
    __shared__ float s[W_][W_ + 1];

    const int tid = threadIdx.x;
    {
        int r  = tid >> 3;
        int c0 = (tid & 7) * 8;
        const bf16* base = qkv + (size_t)(n*W_ + r) * (3*D_) + h*DH_ + c0;
        bf16x8 tq = *(const bf16x8*)(base);
        bf16x8 tk = *(const bf16x8*)(base + D_);
        bf16x8 tv = *(const bf16x8*)(base + 2*D_);
#pragma unroll
        for (int j = 0; j < 8; ++j) {
            q[r][c0 + j] = bf2f(tq[j]);
            k[r][c0 + j] = bf2f(tk[j]);
            v[r][c0 + j] = bf2f(tv[j]);
        }
    }
    __syncthreads();

    const int i = tid >> 3;
    {
        int j0 = (tid & 7) * 4;
#pragma unroll
        for (int jj = 0; jj < 4; ++jj) {
            int j = j0 + jj;
            float d = 0.f;
#pragma unroll
            for (int kk = 0; kk < DH_; ++kk) d += q[i][kk] * k[j][kk];
            s[i][j] = (j <= i) ? d * 0.125f : -1e30f;
        }
    }
    __syncthreads();

    if (tid < W_) {
        float mx = -1e30f;
#pragma unroll
        for (int j = 0; j < W_; ++j) mx = fmaxf(mx, s[tid][j]);
        float sum = 0.f;
#pragma unroll
        for (int j = 0; j < W_; ++j) { float e = __expf(s[tid][j] - mx); s[tid][j] = e; sum += e; }
        float inv = 1.f / sum;
#pragma unroll
        for (int j = 0; j < W_; ++j) s[tid][j] *= inv;
    }
    __syncthreads();

    {
        int d0 = (tid & 7) * 8;
        float o[8] = {0,0,0,0,0,0,0,0};
#pragma unroll
        for (int j = 0; j < W_; ++j) {
            float a = s[i][j];
#pragma unroll
            for (int dd = 0; dd < 8; ++dd) o[dd] += a * v[j][d0 + dd];
        }
        bf16* dst = ctx + (size_t)(n*W_ + i) * D_ + h*DH_ + d0;
#pragma unroll
        for (int dd = 0; dd < 8; ++dd) dst[dd] = __float2bfloat16(o[dd]);
    }
}

// ---------------------------------------------------------------------------
// Head: token = xb[n*32+31,:] bf16; logits (NWIN,6) then values (NWIN)
// ---------------------------------------------------------------------------
__global__ __launch_bounds__(64) void head_kernel(
    const bf16* __restrict__ xb,
    const float* __restrict__ Wp, const float* __restrict__ bp,
    const float* __restrict__ Wv, const float* __restrict__ bv,
    float* __restrict__ out)
{
    const int n    = blockIdx.x;
    const int lane = threadIdx.x;
    const bf16* row = xb + (size_t)(n*W_ + (W_-1)) * D_;
    float t[8];
#pragma unroll
    for (int j = 0; j < 8; ++j) t[j] = bf2f(*(const short*)(row + lane + j*64));

    for (int a = 0; a < A_ + 1; ++a) {
        const float* w = (a < A_) ? (Wp + (size_t)a * D_) : Wv;
        float d = 0.f;
#pragma unroll
        for (int j = 0; j < 8; ++j) d += t[j] * w[lane + j*64];
#pragma unroll
        for (int off = 32; off > 0; off >>= 1) d += __shfl_down(d, off);
        if (lane == 0) {
            if (a < A_) out[(size_t)n*A_ + a] = d + bp[a];
            else        out[(size_t)NWIN*A_ + n] = d + bv[0];
        }
    }
}

// ---------------------------------------------------------------------------
extern "C" void kernel_launch(void* const* d_in, const int* in_sizes, int n_in,
                              void* d_out, int out_size, void* d_ws, size_t ws_size,
                              hipStream_t stream) {
    const float* feats = (const float*)d_in[0];
    const float* pos   = (const float*)d_in[1];
    const float* Wqkv  = (const float*)d_in[2];
    const float* bqkv  = (const float*)d_in[3];
    const float* Wo    = (const float*)d_in[4];
    const float* bo    = (const float*)d_in[5];
    const float* ln1g  = (const float*)d_in[6];
    const float* ln1b  = (const float*)d_in[7];
    const float* W1    = (const float*)d_in[8];
    const float* b1    = (const float*)d_in[9];
    const float* W2    = (const float*)d_in[10];
    const float* b2    = (const float*)d_in[11];
    const float* ln2g  = (const float*)d_in[12];
    const float* ln2b  = (const float*)d_in[13];
    const float* Wp    = (const float*)d_in[14];
    const float* bp    = (const float*)d_in[15];
    const float* Wv    = (const float*)d_in[16];
    const float* bv    = (const float*)d_in[17];
    float* out = (float*)d_out;

    char* basep = (ws_size >= TOTAL_BYTES) ? (char*)d_ws : g_fallback;

    bf16*  xb   = (bf16*)basep;
    bf16*  wq_b = (bf16*)(basep + XB_BYTES);
    bf16*  wo_b = wq_b + WQ_ELEMS;
    bf16*  w1_b = wo_b + WO_ELEMS;
    bf16*  w2_b = w1_b + W1_ELEMS;
    bf16*  scr  = w2_b + W2_ELEMS;
    bf16*  qkv_s = scr;                            // (NTOK, 1536)
    bf16*  ctx_s = scr + (size_t)NTOK * (3*D_);    // (NTOK, 512)
    bf16*  h_s   = scr;                            // (NTOK, 2048) FFN phase

    cvt_kernel<<<(WQ_ELEMS/4 + 255)/256, 256, 0, stream>>>(Wqkv, wq_b, WQ_ELEMS/4);
    cvt_kernel<<<(WO_ELEMS/4 + 255)/256, 256, 0, stream>>>(Wo,   wo_b, WO_ELEMS/4);
    cvt_kernel<<<(W1_ELEMS/4 + 255)/256, 256, 0, stream>>>(W1,   w1_b, W1_ELEMS/4);
    cvt_kernel<<<(W2_ELEMS/4 + 255)/256, 256, 0, stream>>>(W2,   w2_b, W2_ELEMS/4);

    build_x_kernel<<<NTOK * (D_/4) / 256, 256, 0, stream>>>(feats, pos, xb);

    const int GM = NTOK / 128;   // 512 m-blocks (div by 8, XCD remap ok)

    for (int i = 0; i < L_; ++i) {
        const bf16*  wq_i = wq_b + (size_t)i * 3*D_*D_;
        const float* bq_i = bqkv + (size_t)i * 3*D_;
        const bf16*  wo_i = wo_b + (size_t)i * D_*D_;
        const float* bo_i = bo   + (size_t)i * D_;
        const bf16*  w1_i = w1_b + (size_t)i * 4*D_*D_;
        const float* b1_i = b1   + (size_t)i * 4*D_;
        const bf16*  w2_i = w2_b + (size_t)i * 4*D_*D_;
        const float* b2_i = b2   + (size_t)i * D_;

        // qkv = xb @ Wqkv^T + bqkv
        gemm_bf16<false><<<GM * (3*D_/128), 256, 0, stream>>>(
            xb, wq_i, bq_i, qkv_s, NTOK, 3*D_, D_);
        attn_kernel<<<dim3(NWIN, H_), 256, 0, stream>>>(qkv_s, ctx_s);
        // xb = LN1(xb + ctx @ Wo^T + bo)   (fused, in place)
        gemm_ln<<<NTOK/32, 256, 0, stream>>>(
            ctx_s, wo_i, bo_i, xb, xb,
            ln1g + (size_t)i*D_, ln1b + (size_t)i*D_, D_);
        // h = relu(xb @ W1^T + b1)
        gemm_bf16<true><<<GM * (4*D_/128), 256, 0, stream>>>(
            xb, w1_i, b1_i, h_s, NTOK, 4*D_, D_);
        // xb = LN2(xb + h @ W2^T + b2)     (fused, in place)
        gemm_ln<<<NTOK/32, 256, 0, stream>>>(
            h_s, w2_i, b2_i, xb, xb,
            ln2g + (size_t)i*D_, ln2b + (size_t)i*D_, 4*D_);
    }

    head_kernel<<<NWIN, 64, 0, stream>>>(xb, Wp, bp, Wv, bv, out);
}

// Round 12
// 4205.684 us; speedup vs baseline: 1.0217x; 1.0217x over previous
//
#include <hip/hip_runtime.h>
#include <hip/hip_bf16.h>
#include <cstdint>
#include <cstddef>

// Problem constants (fixed by reference)
#define B_    8
#define T_    256
#define D_    512
#define W_    32
#define L_    4
#define A_    6
#define H_    8
#define DH_   64
#define DHP   65                 // padded LDS row (attn bank-conflict fix, R5)
#define NWIN  (B_*T_)            // 2048 windows
#define NTOK  (NWIN*W_)          // 65536 token rows

typedef __hip_bfloat16 bf16;
using bf16x8 = __attribute__((ext_vector_type(8))) short;  // MFMA A/B frag (4 VGPR)
using f32x4  = __attribute__((ext_vector_type(4))) float;  // MFMA C/D frag

// ---- memory plan (bytes): bf16-only residual stream ----------------------
#define XB_BYTES  ((size_t)NTOK * D_ * 2)     // 64 MiB bf16 residual master
#define WQ_ELEMS  ((size_t)L_ * 3*D_*D_)
#define WO_ELEMS  ((size_t)L_ * D_*D_)
#define W1_ELEMS  ((size_t)L_ * 4*D_*D_)
#define W2_ELEMS  ((size_t)L_ * 4*D_*D_)
#define WB_BYTES  ((WQ_ELEMS + WO_ELEMS + W1_ELEMS + W2_ELEMS) * 2)
#define SCR_BYTES ((size_t)NTOK * 2048 * 2)   // qkv(1536)+ctx(512) / h(2048)
#define TOTAL_BYTES (XB_BYTES + WB_BYTES + SCR_BYTES)

static char* g_fallback = nullptr;
__attribute__((constructor)) static void alloc_fallback() {
    (void)hipMalloc((void**)&g_fallback, TOTAL_BYTES);
}

// ---- async global->LDS (16B per lane; LDS dest = wave base + lane*16) -----
typedef __attribute__((address_space(3))) uint8_t* as3p;
typedef const __attribute__((address_space(1))) uint8_t* as1p;
__device__ __forceinline__ void gload_lds16(const void* g, void* l) {
    __builtin_amdgcn_global_load_lds((as1p)(const uint8_t*)g,
                                     (as3p)(uint32_t)(uintptr_t)l, 16, 0, 0);
}

__device__ __forceinline__ float bf2f(short s) {
    return __uint_as_float(((uint32_t)(uint16_t)s) << 16);
}

// s_waitcnt immediates (gfx9 lineage): vm[3:0]|[15:14], exp[6:4], lgkm[11:8]
#define WAITCNT_VM10  0x0F7A   // vmcnt<=10, exp/lgkm unconstrained
#define WAITCNT_VM0   0x0F70   // vmcnt==0,  exp/lgkm unconstrained

// ---------------------------------------------------------------------------
// weight convert fp32 -> bf16 (4 elems/thread)
// ---------------------------------------------------------------------------
__global__ __launch_bounds__(256) void cvt_kernel(
    const float* __restrict__ w, bf16* __restrict__ o, int n4)
{
    int i = blockIdx.x * 256 + threadIdx.x;
    if (i >= n4) return;
    float4 f = ((const float4*)w)[i];
    bf16* d = o + (size_t)i * 4;
    d[0] = __float2bfloat16(f.x);
    d[1] = __float2bfloat16(f.y);
    d[2] = __float2bfloat16(f.z);
    d[3] = __float2bfloat16(f.w);
}

// ---------------------------------------------------------------------------
// build_x: xb[n*32+w,:] = bf16(feats[b, max(t+w-31,0),:] + pos[w,:])
// ---------------------------------------------------------------------------
__global__ __launch_bounds__(256) void build_x_kernel(
    const float* __restrict__ feats,
    const float* __restrict__ pos,
    bf16* __restrict__ xb)
{
    int gid   = blockIdx.x * 256 + threadIdx.x;   // over NTOK * (D/4)
    int token = gid >> 7;
    int c4    = (gid & 127) * 4;
    int w     = token & (W_-1);
    int n     = token >> 5;
    int t     = n & (T_-1);
    int b     = n >> 8;
    int frame = t + w - (W_-1); if (frame < 0) frame = 0;
    const float4 f = *(const float4*)(feats + ((size_t)(b*T_ + frame)*D_ + c4));
    const float4 p = *(const float4*)(pos   + ((size_t)w*D_ + c4));
    bf16* d = xb + (size_t)token*D_ + c4;
    d[0] = __float2bfloat16(f.x + p.x);
    d[1] = __float2bfloat16(f.y + p.y);
    d[2] = __float2bfloat16(f.z + p.z);
    d[3] = __float2bfloat16(f.w + p.w);
}

// ---------------------------------------------------------------------------
// bf16 MFMA GEMM (BK=32): Cb = bf16(A(MxK) @ Bt(NxK)^T + bias [relu])
// 128x128 tile, 4 waves, wave 64x64 (4x4 of 16x16x32 MFMA).
// 1-D grid + XCD remap (R7: same-A-stripe blocks share one XCD L2).
// ---------------------------------------------------------------------------
template<bool RELU>
__global__ __launch_bounds__(256) void gemm_bf16(
    const bf16* __restrict__ A,
    const bf16* __restrict__ Bt,
    const float* __restrict__ bias,
    bf16* __restrict__ Cb,
    int M, int N, int K)
{
    __shared__ bf16 As[128*32];   // [row][k] row-major, 64B rows
    __shared__ bf16 Bs[128*32];

    const int tid  = threadIdx.x;
    const int lane = tid & 63;
    const int wv   = tid >> 6;

    // XCD-aware block remap (gridM % 8 == 0)
    const int gridN = N >> 7;
    const int bid   = blockIdx.x;
    const int q_    = bid >> 3;
    const int n0    = (q_ % gridN) << 7;
    const int m0    = (((q_ / gridN) * 8) + (bid & 7)) << 7;

    const int wm   = (wv >> 1) * 64;
    const int wn   = (wv & 1) * 64;

    f32x4 acc[4][4] = {};

    const int   srow  = wv*16 + (lane >> 2);
    const int   skoff = (lane & 3) * 8;
    const bf16* ga0 = A  + (size_t)(m0 + srow)      * K + skoff;
    const bf16* ga1 = A  + (size_t)(m0 + 64 + srow) * K + skoff;
    const bf16* gb0 = Bt + (size_t)(n0 + srow)      * K + skoff;
    const bf16* gb1 = Bt + (size_t)(n0 + 64 + srow) * K + skoff;
    char* lAs = (char*)As;
    char* lBs = (char*)Bs;
    const int l0 = wv*1024 + lane*16;

    const int fr = lane & 15;
    const int fq = (lane >> 4) * 16;

    for (int k0 = 0; k0 < K; k0 += 32) {
        gload_lds16(ga0 + k0, lAs + l0);
        gload_lds16(ga1 + k0, lAs + l0 + 4096);
        gload_lds16(gb0 + k0, lBs + l0);
        gload_lds16(gb1 + k0, lBs + l0 + 4096);
        __syncthreads();

        bf16x8 av[4], bv[4];
#pragma unroll
        for (int i = 0; i < 4; ++i) {
            av[i] = *(const bf16x8*)(lAs + (wm + i*16 + fr)*64 + fq);
            bv[i] = *(const bf16x8*)(lBs + (wn + i*16 + fr)*64 + fq);
        }
#pragma unroll
        for (int i = 0; i < 4; ++i)
#pragma unroll
            for (int j = 0; j < 4; ++j)
                acc[i][j] = __builtin_amdgcn_mfma_f32_16x16x32_bf16(
                    av[i], bv[j], acc[i][j], 0, 0, 0);
        __syncthreads();
    }

    // epilogue: C/D layout col=lane&15, row=(lane>>4)*4+reg
    const int er = (lane >> 4) * 4;
    const int ec = lane & 15;
#pragma unroll
    for (int i = 0; i < 4; ++i) {
#pragma unroll
        for (int j = 0; j < 4; ++j) {
            const int ncol = n0 + wn + j*16 + ec;
            const float bv_ = bias[ncol];
#pragma unroll
            for (int r = 0; r < 4; ++r) {
                const int mrow = m0 + wm + i*16 + er + r;
                float v = acc[i][j][r] + bv_;
                if (RELU) v = fmaxf(v, 0.f);
                Cb[(size_t)mrow * N + ncol] = __float2bfloat16(v);
            }
        }
    }
}

// ---------------------------------------------------------------------------
// Fused residual GEMM + LayerNorm — R12: wave-private DOUBLE-BUFFERED staging
// with partial vmcnt waits (AITER-style; the pipeline R11 failed to express).
//   y = xres + A @ Bt^T + bias;  xout = LN(y) * g + b    (N fixed = 512)
// 32 rows x 512 cols per block; wave wv owns cols [wv*128, +128) (disjoint).
// Per wave: 2 bufs x (A 2 KB + B 8 KB). Loop: stage iter k+1 into buf
// (k+1)&1, THEN s_waitcnt vmcnt(10) (= iter k's 10 loads retired), compute
// from buf k&1. No block barrier in K-loop. Exposed HBM latency per step
// ~900 -> ~900-(loop body ~400). LDS = 4x20 KB = 80 KB -> 2 blocks/CU; the
// LN red array ALIASES each wave's B-buf0 (dead after final odd-index step;
// NSTEP is even for K=512/2048). Single barrier in epilogue for LN.
// In-place xres==xout safe: each block reads/writes only its own 32 rows.
// ---------------------------------------------------------------------------
template<int K>
__global__ __launch_bounds__(256) void gemm_ln(
    const bf16* __restrict__ A,     // (M x K)
    const bf16* __restrict__ Bt,    // (512 x K)
    const float* __restrict__ bias, // (512)
    const bf16* xres,               // (M x 512), aliases xout
    bf16* xout,
    const float* __restrict__ g,
    const float* __restrict__ b)
{
    constexpr int NSTEP = K / 32;          // 16 or 64 (even)
    __shared__ char smem[81920];           // 4 waves x (2x2KB A + 2x8KB B)

    const int tid  = threadIdx.x;
    const int lane = tid & 63;
    const int wv   = tid >> 6;
    const int m0   = (gridDim.x - 1 - blockIdx.x) * 32;
    const int wc   = wv * 128;             // wave col offset

    f32x4 acc[2][8] = {};

    const int sr  = lane >> 2;             // staging row in 16-row group
    const int sc  = (lane & 3) * 8;        // staging k-offset (elems)
    char* wb = smem + wv * 20480;
    char* lA0 = wb;                        // 2 KB
    char* lA1 = wb + 2048;
    char* lB0 = wb + 4096;                 // 8 KB (aliased by red post-loop)
    char* lB1 = wb + 12288;
    const int dst = lane * 16;

    const bf16* gA0 = A  + (size_t)(m0 + sr)      * K + sc;
    const bf16* gA1 = A  + (size_t)(m0 + 16 + sr) * K + sc;
    const bf16* gB  = Bt + (size_t)(wc + sr)      * K + sc;

    auto stage = [&](int k0, char* la, char* lb) {
        gload_lds16(gA0 + k0, la + dst);
        gload_lds16(gA1 + k0, la + 1024 + dst);
#pragma unroll
        for (int jj = 0; jj < 8; ++jj)
            gload_lds16(gB + (size_t)(jj*16) * K + k0, lb + jj*1024 + dst);
    };

    const int fr = lane & 15;
    const int fq = (lane >> 4) * 16;

    stage(0, lA0, lB0);                    // prologue: iter 0 in flight

#pragma unroll 2
    for (int k = 0; k < NSTEP; ++k) {
        if (k + 1 < NSTEP) {
            // issue next iter FIRST, then wait only for current iter's 10
            if ((k + 1) & 1) stage((k+1)*32, lA1, lB1);
            else             stage((k+1)*32, lA0, lB0);
            __builtin_amdgcn_s_waitcnt(WAITCNT_VM10);
        } else {
            __builtin_amdgcn_s_waitcnt(WAITCNT_VM0);
        }
        char* la = (k & 1) ? lA1 : lA0;
        char* lb = (k & 1) ? lB1 : lB0;

        bf16x8 av[2], bv[8];
#pragma unroll
        for (int i = 0; i < 2; ++i)
            av[i] = *(const bf16x8*)(la + (i*16 + fr)*64 + fq);
#pragma unroll
        for (int j = 0; j < 8; ++j)
            bv[j] = *(const bf16x8*)(lb + (j*16 + fr)*64 + fq);
#pragma unroll
        for (int i = 0; i < 2; ++i)
#pragma unroll
            for (int j = 0; j < 8; ++j)
                acc[i][j] = __builtin_amdgcn_mfma_f32_16x16x32_bf16(
                    av[i], bv[j], acc[i][j], 0, 0, 0);
    }

    // ---- epilogue: v = acc + bias + resid; LN over the 512-wide row ----
    // red[wv] aliases this wave's B-buf0 (dead: final step NSTEP-1 is odd ->
    // read from lB1; lB0's last ds_reads completed before their MFMAs).
    float* red_w = (float*)lB0;            // [32][2] per wave
    const int er = (lane >> 4) * 4;
    const int ec = lane & 15;

    float bias_j[8];
#pragma unroll
    for (int j = 0; j < 8; ++j) bias_j[j] = bias[wc + j*16 + ec];

#pragma unroll
    for (int i = 0; i < 2; ++i) {
#pragma unroll
        for (int r = 0; r < 4; ++r) {
            const int row = i*16 + er + r;
            const bf16* xr = xres + (size_t)(m0 + row) * D_ + wc + ec;
            float s1 = 0.f, s2 = 0.f;
#pragma unroll
            for (int j = 0; j < 8; ++j) {
                float v = acc[i][j][r] + bias_j[j] + bf2f(*(const short*)(xr + j*16));
                acc[i][j][r] = v;
                s1 += v; s2 += v*v;
            }
#pragma unroll
            for (int mask = 1; mask < 16; mask <<= 1) {
                s1 += __shfl_xor(s1, mask, 64);
                s2 += __shfl_xor(s2, mask, 64);
            }
            if (ec == 0) { red_w[row*2 + 0] = s1; red_w[row*2 + 1] = s2; }
        }
    }
    __syncthreads();   // single barrier: cross-wave LN reduction

#pragma unroll
    for (int i = 0; i < 2; ++i) {
#pragma unroll
        for (int r = 0; r < 4; ++r) {
            const int row = i*16 + er + r;
            float t1 = 0.f, t2 = 0.f;
#pragma unroll
            for (int w = 0; w < 4; ++w) {
                const float* rw = (const float*)(smem + w*20480 + 4096);
                t1 += rw[row*2 + 0];
                t2 += rw[row*2 + 1];
            }
            const float mu  = t1 * (1.f / D_);
            float var = t2 * (1.f / D_) - mu * mu;
            if (var < 0.f) var = 0.f;
            const float rs = rsqrtf(var + 1e-5f);
            bf16* xo = xout + (size_t)(m0 + row) * D_ + wc + ec;
#pragma unroll
            for (int j = 0; j < 8; ++j) {
                const int col = wc + j*16 + ec;
                float o = (acc[i][j][r] - mu) * rs * g[col] + b[col];
                xo[j*16] = __float2bfloat16(o);
            }
        }
    }
}

// ---------------------------------------------------------------------------
// Attention: block per (window, head); bf16 qkv in, bf16 ctx out; fp32 inside.
// LDS rows padded to DHP=65 floats (R5 bank-conflict fix).
// ---------------------------------------------------------------------------
__global__ __launch_bounds__(256) void attn_kernel(
    const bf16* __restrict__ qkv,
    bf16* __restrict__ ctx)
{
    const int n = blockIdx.x;
    const int h = blockIdx.y;
    __shared__ float q[W_][DHP];
    __shared__ float k[W_][DHP];
    __shared__ float v[W_][DHP];
    __shared__ float s[W_][W_ + 1];

    const int tid = threadIdx.x;
    {
        int r  = tid >> 3;
        int c0 = (tid & 7) * 8;
        const bf16* base = qkv + (size_t)(n*W_ + r) * (3*D_) + h*DH_ + c0;
        bf16x8 tq = *(const bf16x8*)(base);
        bf16x8 tk = *(const bf16x8*)(base + D_);
        bf16x8 tv = *(const bf16x8*)(base + 2*D_);
#pragma unroll
        for (int j = 0; j < 8; ++j) {
            q[r][c0 + j] = bf2f(tq[j]);
            k[r][c0 + j] = bf2f(tk[j]);
            v[r][c0 + j] = bf2f(tv[j]);
        }
    }
    __syncthreads();

    const int i = tid >> 3;
    {
        int j0 = (tid & 7) * 4;
#pragma unroll
        for (int jj = 0; jj < 4; ++jj) {
            int j = j0 + jj;
            float d = 0.f;
#pragma unroll
            for (int kk = 0; kk < DH_; ++kk) d += q[i][kk] * k[j][kk];
            s[i][j] = (j <= i) ? d * 0.125f : -1e30f;
        }
    }
    __syncthreads();

    if (tid < W_) {
        float mx = -1e30f;
#pragma unroll
        for (int j = 0; j < W_; ++j) mx = fmaxf(mx, s[tid][j]);
        float sum = 0.f;
#pragma unroll
        for (int j = 0; j < W_; ++j) { float e = __expf(s[tid][j] - mx); s[tid][j] = e; sum += e; }
        float inv = 1.f / sum;
#pragma unroll
        for (int j = 0; j < W_; ++j) s[tid][j] *= inv;
    }
    __syncthreads();

    {
        int d0 = (tid & 7) * 8;
        float o[8] = {0,0,0,0,0,0,0,0};
#pragma unroll
        for (int j = 0; j < W_; ++j) {
            float a = s[i][j];
#pragma unroll
            for (int dd = 0; dd < 8; ++dd) o[dd] += a * v[j][d0 + dd];
        }
        bf16* dst = ctx + (size_t)(n*W_ + i) * D_ + h*DH_ + d0;
#pragma unroll
        for (int dd = 0; dd < 8; ++dd) dst[dd] = __float2bfloat16(o[dd]);
    }
}

// ---------------------------------------------------------------------------
// Head: token = xb[n*32+31,:] bf16; logits (NWIN,6) then values (NWIN)
// ---------------------------------------------------------------------------
__global__ __launch_bounds__(64) void head_kernel(
    const bf16* __restrict__ xb,
    const float* __restrict__ Wp, const float* __restrict__ bp,
    const float* __restrict__ Wv, const float* __restrict__ bv,
    float* __restrict__ out)
{
    const int n    = blockIdx.x;
    const int lane = threadIdx.x;
    const bf16* row = xb + (size_t)(n*W_ + (W_-1)) * D_;
    float t[8];
#pragma unroll
    for (int j = 0; j < 8; ++j) t[j] = bf2f(*(const short*)(row + lane + j*64));

    for (int a = 0; a < A_ + 1; ++a) {
        const float* w = (a < A_) ? (Wp + (size_t)a * D_) : Wv;
        float d = 0.f;
#pragma unroll
        for (int j = 0; j < 8; ++j) d += t[j] * w[lane + j*64];
#pragma unroll
        for (int off = 32; off > 0; off >>= 1) d += __shfl_down(d, off);
        if (lane == 0) {
            if (a < A_) out[(size_t)n*A_ + a] = d + bp[a];
            else        out[(size_t)NWIN*A_ + n] = d + bv[0];
        }
    }
}

// ---------------------------------------------------------------------------
extern "C" void kernel_launch(void* const* d_in, const int* in_sizes, int n_in,
                              void* d_out, int out_size, void* d_ws, size_t ws_size,
                              hipStream_t stream) {
    const float* feats = (const float*)d_in[0];
    const float* pos   = (const float*)d_in[1];
    const float* Wqkv  = (const float*)d_in[2];
    const float* bqkv  = (const float*)d_in[3];
    const float* Wo    = (const float*)d_in[4];
    const float* bo    = (const float*)d_in[5];
    const float* ln1g  = (const float*)d_in[6];
    const float* ln1b  = (const float*)d_in[7];
    const float* W1    = (const float*)d_in[8];
    const float* b1    = (const float*)d_in[9];
    const float* W2    = (const float*)d_in[10];
    const float* b2    = (const float*)d_in[11];
    const float* ln2g  = (const float*)d_in[12];
    const float* ln2b  = (const float*)d_in[13];
    const float* Wp    = (const float*)d_in[14];
    const float* bp    = (const float*)d_in[15];
    const float* Wv    = (const float*)d_in[16];
    const float* bv    = (const float*)d_in[17];
    float* out = (float*)d_out;

    char* basep = (ws_size >= TOTAL_BYTES) ? (char*)d_ws : g_fallback;

    bf16*  xb   = (bf16*)basep;
    bf16*  wq_b = (bf16*)(basep + XB_BYTES);
    bf16*  wo_b = wq_b + WQ_ELEMS;
    bf16*  w1_b = wo_b + WO_ELEMS;
    bf16*  w2_b = w1_b + W1_ELEMS;
    bf16*  scr  = w2_b + W2_ELEMS;
    bf16*  qkv_s = scr;                            // (NTOK, 1536)
    bf16*  ctx_s = scr + (size_t)NTOK * (3*D_);    // (NTOK, 512)
    bf16*  h_s   = scr;                            // (NTOK, 2048) FFN phase

    cvt_kernel<<<(WQ_ELEMS/4 + 255)/256, 256, 0, stream>>>(Wqkv, wq_b, WQ_ELEMS/4);
    cvt_kernel<<<(WO_ELEMS/4 + 255)/256, 256, 0, stream>>>(Wo,   wo_b, WO_ELEMS/4);
    cvt_kernel<<<(W1_ELEMS/4 + 255)/256, 256, 0, stream>>>(W1,   w1_b, W1_ELEMS/4);
    cvt_kernel<<<(W2_ELEMS/4 + 255)/256, 256, 0, stream>>>(W2,   w2_b, W2_ELEMS/4);

    build_x_kernel<<<NTOK * (D_/4) / 256, 256, 0, stream>>>(feats, pos, xb);

    const int GM = NTOK / 128;   // 512 m-blocks (div by 8, XCD remap ok)

    for (int i = 0; i < L_; ++i) {
        const bf16*  wq_i = wq_b + (size_t)i * 3*D_*D_;
        const float* bq_i = bqkv + (size_t)i * 3*D_;
        const bf16*  wo_i = wo_b + (size_t)i * D_*D_;
        const float* bo_i = bo   + (size_t)i * D_;
        const bf16*  w1_i = w1_b + (size_t)i * 4*D_*D_;
        const float* b1_i = b1   + (size_t)i * 4*D_;
        const bf16*  w2_i = w2_b + (size_t)i * 4*D_*D_;
        const float* b2_i = b2   + (size_t)i * D_;

        // qkv = xb @ Wqkv^T + bqkv
        gemm_bf16<false><<<GM * (3*D_/128), 256, 0, stream>>>(
            xb, wq_i, bq_i, qkv_s, NTOK, 3*D_, D_);
        attn_kernel<<<dim3(NWIN, H_), 256, 0, stream>>>(qkv_s, ctx_s);
        // xb = LN1(xb + ctx @ Wo^T + bo)   (fused, in place)
        gemm_ln<D_><<<NTOK/32, 256, 0, stream>>>(
            ctx_s, wo_i, bo_i, xb, xb,
            ln1g + (size_t)i*D_, ln1b + (size_t)i*D_);
        // h = relu(xb @ W1^T + b1)
        gemm_bf16<true><<<GM * (4*D_/128), 256, 0, stream>>>(
            xb, w1_i, b1_i, h_s, NTOK, 4*D_, D_);
        // xb = LN2(xb + h @ W2^T + b2)     (fused, in place)
        gemm_ln<4*D_><<<NTOK/32, 256, 0, stream>>>(
            h_s, w2_i, b2_i, xb, xb,
            ln2g + (size_t)i*D_, ln2b + (size_t)i*D_);
    }

    head_kernel<<<NWIN, 64, 0, stream>>>(xb, Wp, bp, Wv, bv, out);
}

// Round 13
// 3818.822 us; speedup vs baseline: 1.1252x; 1.1013x over previous
//
#include <hip/hip_runtime.h>
#include <hip/hip_bf16.h>
#include <cstdint>
#include <cstddef>

// Problem constants (fixed by reference)
#define B_    8
#define T_    256
#define D_    512
#define W_    32
#define L_    4
#define A_    6
#define H_    8
#define DH_   64
#define DHP   65                 // padded LDS row (attn bank-conflict fix, R5)
#define NWIN  (B_*T_)            // 2048 windows
#define NTOK  (NWIN*W_)          // 65536 token rows

typedef __hip_bfloat16 bf16;
using bf16x8 = __attribute__((ext_vector_type(8))) short;  // MFMA A/B frag (4 VGPR)
using f32x4  = __attribute__((ext_vector_type(4))) float;  // MFMA C/D frag

// ---- memory plan (bytes): bf16-only residual stream ----------------------
// scr columns: attn phase qkv(1536)+ctx(512)+y(512); FFN phase h(2048)+y(512)
#define XB_BYTES  ((size_t)NTOK * D_ * 2)     // 64 MiB bf16 residual master
#define WQ_ELEMS  ((size_t)L_ * 3*D_*D_)
#define WO_ELEMS  ((size_t)L_ * D_*D_)
#define W1_ELEMS  ((size_t)L_ * 4*D_*D_)
#define W2_ELEMS  ((size_t)L_ * 4*D_*D_)
#define WB_BYTES  ((WQ_ELEMS + WO_ELEMS + W1_ELEMS + W2_ELEMS) * 2)
#define SCR_BYTES ((size_t)NTOK * 2560 * 2)   // 335 MB
#define TOTAL_BYTES (XB_BYTES + WB_BYTES + SCR_BYTES)

static char* g_fallback = nullptr;
__attribute__((constructor)) static void alloc_fallback() {
    (void)hipMalloc((void**)&g_fallback, TOTAL_BYTES);
}

// ---- async global->LDS (16B per lane; LDS dest = wave base + lane*16) -----
typedef __attribute__((address_space(3))) uint8_t* as3p;
typedef const __attribute__((address_space(1))) uint8_t* as1p;
__device__ __forceinline__ void gload_lds16(const void* g, void* l) {
    __builtin_amdgcn_global_load_lds((as1p)(const uint8_t*)g,
                                     (as3p)(uint32_t)(uintptr_t)l, 16, 0, 0);
}

__device__ __forceinline__ float bf2f(short s) {
    return __uint_as_float(((uint32_t)(uint16_t)s) << 16);
}

// ---------------------------------------------------------------------------
// weight convert fp32 -> bf16 (4 elems/thread)
// ---------------------------------------------------------------------------
__global__ __launch_bounds__(256) void cvt_kernel(
    const float* __restrict__ w, bf16* __restrict__ o, int n4)
{
    int i = blockIdx.x * 256 + threadIdx.x;
    if (i >= n4) return;
    float4 f = ((const float4*)w)[i];
    bf16* d = o + (size_t)i * 4;
    d[0] = __float2bfloat16(f.x);
    d[1] = __float2bfloat16(f.y);
    d[2] = __float2bfloat16(f.z);
    d[3] = __float2bfloat16(f.w);
}

// ---------------------------------------------------------------------------
// build_x: xb[n*32+w,:] = bf16(feats[b, max(t+w-31,0),:] + pos[w,:])
// ---------------------------------------------------------------------------
__global__ __launch_bounds__(256) void build_x_kernel(
    const float* __restrict__ feats,
    const float* __restrict__ pos,
    bf16* __restrict__ xb)
{
    int gid   = blockIdx.x * 256 + threadIdx.x;   // over NTOK * (D/4)
    int token = gid >> 7;
    int c4    = (gid & 127) * 4;
    int w     = token & (W_-1);
    int n     = token >> 5;
    int t     = n & (T_-1);
    int b     = n >> 8;
    int frame = t + w - (W_-1); if (frame < 0) frame = 0;
    const float4 f = *(const float4*)(feats + ((size_t)(b*T_ + frame)*D_ + c4));
    const float4 p = *(const float4*)(pos   + ((size_t)w*D_ + c4));
    bf16* d = xb + (size_t)token*D_ + c4;
    d[0] = __float2bfloat16(f.x + p.x);
    d[1] = __float2bfloat16(f.y + p.y);
    d[2] = __float2bfloat16(f.z + p.z);
    d[3] = __float2bfloat16(f.w + p.w);
}

// ---------------------------------------------------------------------------
// bf16 MFMA GEMM (BK=32, proven ~600 TF at K=512 shapes):
// Cb = bf16(A(MxK) @ Bt(NxK)^T + bias [relu])
// 128x128 tile, 4 waves, wave 64x64 (4x4 of 16x16x32 MFMA).
// 1-D grid + XCD remap (R7: same-A-stripe blocks share one XCD L2).
// ---------------------------------------------------------------------------
template<bool RELU>
__global__ __launch_bounds__(256) void gemm_bf16(
    const bf16* __restrict__ A,
    const bf16* __restrict__ Bt,
    const float* __restrict__ bias,
    bf16* __restrict__ Cb,
    int M, int N, int K)
{
    __shared__ bf16 As[128*32];   // [row][k] row-major, 64B rows
    __shared__ bf16 Bs[128*32];

    const int tid  = threadIdx.x;
    const int lane = tid & 63;
    const int wv   = tid >> 6;

    // XCD-aware block remap (gridM % 8 == 0)
    const int gridN = N >> 7;
    const int bid   = blockIdx.x;
    const int q_    = bid >> 3;
    const int n0    = (q_ % gridN) << 7;
    const int m0    = (((q_ / gridN) * 8) + (bid & 7)) << 7;

    const int wm   = (wv >> 1) * 64;
    const int wn   = (wv & 1) * 64;

    f32x4 acc[4][4] = {};

    const int   srow  = wv*16 + (lane >> 2);
    const int   skoff = (lane & 3) * 8;
    const bf16* ga0 = A  + (size_t)(m0 + srow)      * K + skoff;
    const bf16* ga1 = A  + (size_t)(m0 + 64 + srow) * K + skoff;
    const bf16* gb0 = Bt + (size_t)(n0 + srow)      * K + skoff;
    const bf16* gb1 = Bt + (size_t)(n0 + 64 + srow) * K + skoff;
    char* lAs = (char*)As;
    char* lBs = (char*)Bs;
    const int l0 = wv*1024 + lane*16;

    const int fr = lane & 15;
    const int fq = (lane >> 4) * 16;

    for (int k0 = 0; k0 < K; k0 += 32) {
        gload_lds16(ga0 + k0, lAs + l0);
        gload_lds16(ga1 + k0, lAs + l0 + 4096);
        gload_lds16(gb0 + k0, lBs + l0);
        gload_lds16(gb1 + k0, lBs + l0 + 4096);
        __syncthreads();

        bf16x8 av[4], bv[4];
#pragma unroll
        for (int i = 0; i < 4; ++i) {
            av[i] = *(const bf16x8*)(lAs + (wm + i*16 + fr)*64 + fq);
            bv[i] = *(const bf16x8*)(lBs + (wn + i*16 + fr)*64 + fq);
        }
#pragma unroll
        for (int i = 0; i < 4; ++i)
#pragma unroll
            for (int j = 0; j < 4; ++j)
                acc[i][j] = __builtin_amdgcn_mfma_f32_16x16x32_bf16(
                    av[i], bv[j], acc[i][j], 0, 0, 0);
        __syncthreads();
    }

    // epilogue: C/D layout col=lane&15, row=(lane>>4)*4+reg
    const int er = (lane >> 4) * 4;
    const int ec = lane & 15;
#pragma unroll
    for (int i = 0; i < 4; ++i) {
#pragma unroll
        for (int j = 0; j < 4; ++j) {
            const int ncol = n0 + wn + j*16 + ec;
            const float bv_ = bias[ncol];
#pragma unroll
            for (int r = 0; r < 4; ++r) {
                const int mrow = m0 + wm + i*16 + er + r;
                float v = acc[i][j][r] + bv_;
                if (RELU) v = fmaxf(v, 0.f);
                Cb[(size_t)mrow * N + ncol] = __float2bfloat16(v);
            }
        }
    }
}

// ---------------------------------------------------------------------------
// Fused residual-add + LayerNorm (bandwidth-bound, ~192 MB/call):
//   xb = LN(y + xb) * g + b     (in place on xb; y is the GEMM output)
// One wave per token; lane holds 8 consecutive cols (lane*8). bf16x8 I/O.
// ---------------------------------------------------------------------------
__global__ __launch_bounds__(256) void lnres_kernel(
    const bf16* __restrict__ y,
    bf16* xb,
    const float* __restrict__ g,
    const float* __restrict__ b)
{
    const int wave  = threadIdx.x >> 6;
    const int lane  = threadIdx.x & 63;
    const int token = blockIdx.x * 4 + wave;
    const int c0    = lane * 8;

    const bf16* yr = y  + (size_t)token * D_ + c0;
    bf16*       xr = xb + (size_t)token * D_ + c0;

    bf16x8 ty = *(const bf16x8*)yr;
    bf16x8 tx = *(const bf16x8*)xr;

    float v[8];
    float s1 = 0.f, s2 = 0.f;
#pragma unroll
    for (int j = 0; j < 8; ++j) {
        v[j] = bf2f(ty[j]) + bf2f(tx[j]);
        s1 += v[j]; s2 += v[j]*v[j];
    }
#pragma unroll
    for (int mask = 1; mask < 64; mask <<= 1) {
        s1 += __shfl_xor(s1, mask);
        s2 += __shfl_xor(s2, mask);
    }
    const float mu = s1 * (1.f / D_);
    float var = s2 * (1.f / D_) - mu * mu;
    if (var < 0.f) var = 0.f;
    const float rs = rsqrtf(var + 1e-5f);

    const float4 g0 = *(const float4*)(g + c0);
    const float4 g1 = *(const float4*)(g + c0 + 4);
    const float4 b0 = *(const float4*)(b + c0);
    const float4 b1 = *(const float4*)(b + c0 + 4);
    const float gg[8] = {g0.x,g0.y,g0.z,g0.w,g1.x,g1.y,g1.z,g1.w};
    const float bb[8] = {b0.x,b0.y,b0.z,b0.w,b1.x,b1.y,b1.z,b1.w};

    bf16x8 o;
#pragma unroll
    for (int j = 0; j < 8; ++j) {
        float t = (v[j] - mu) * rs * gg[j] + bb[j];
        o[j] = (short)__bfloat16_as_ushort(__float2bfloat16(t));
    }
    *(bf16x8*)xr = o;
}

// ---------------------------------------------------------------------------
// Attention: block per (window, head); bf16 qkv in, bf16 ctx out; fp32 inside.
// LDS rows padded to DHP=65 floats (R5 bank-conflict fix).
// ---------------------------------------------------------------------------
__global__ __launch_bounds__(256) void attn_kernel(
    const bf16* __restrict__ qkv,
    bf16* __restrict__ ctx)
{
    const int n = blockIdx.x;
    const int h = blockIdx.y;
    __shared__ float q[W_][DHP];
    __shared__ float k[W_][DHP];
    __shared__ float v[W_][DHP];
    __shared__ float s[W_][W_ + 1];

    const int tid = threadIdx.x;
    {
        int r  = tid >> 3;
        int c0 = (tid & 7) * 8;
        const bf16* base = qkv + (size_t)(n*W_ + r) * (3*D_) + h*DH_ + c0;
        bf16x8 tq = *(const bf16x8*)(base);
        bf16x8 tk = *(const bf16x8*)(base + D_);
        bf16x8 tv = *(const bf16x8*)(base + 2*D_);
#pragma unroll
        for (int j = 0; j < 8; ++j) {
            q[r][c0 + j] = bf2f(tq[j]);
            k[r][c0 + j] = bf2f(tk[j]);
            v[r][c0 + j] = bf2f(tv[j]);
        }
    }
    __syncthreads();

    const int i = tid >> 3;
    {
        int j0 = (tid & 7) * 4;
#pragma unroll
        for (int jj = 0; jj < 4; ++jj) {
            int j = j0 + jj;
            float d = 0.f;
#pragma unroll
            for (int kk = 0; kk < DH_; ++kk) d += q[i][kk] * k[j][kk];
            s[i][j] = (j <= i) ? d * 0.125f : -1e30f;
        }
    }
    __syncthreads();

    if (tid < W_) {
        float mx = -1e30f;
#pragma unroll
        for (int j = 0; j < W_; ++j) mx = fmaxf(mx, s[tid][j]);
        float sum = 0.f;
#pragma unroll
        for (int j = 0; j < W_; ++j) { float e = __expf(s[tid][j] - mx); s[tid][j] = e; sum += e; }
        float inv = 1.f / sum;
#pragma unroll
        for (int j = 0; j < W_; ++j) s[tid][j] *= inv;
    }
    __syncthreads();

    {
        int d0 = (tid & 7) * 8;
        float o[8] = {0,0,0,0,0,0,0,0};
#pragma unroll
        for (int j = 0; j < W_; ++j) {
            float a = s[i][j];
#pragma unroll
            for (int dd = 0; dd < 8; ++dd) o[dd] += a * v[j][d0 + dd];
        }
        bf16* dst = ctx + (size_t)(n*W_ + i) * D_ + h*DH_ + d0;
#pragma unroll
        for (int dd = 0; dd < 8; ++dd) dst[dd] = __float2bfloat16(o[dd]);
    }
}

// ---------------------------------------------------------------------------
// Head: token = xb[n*32+31,:] bf16; logits (NWIN,6) then values (NWIN)
// ---------------------------------------------------------------------------
__global__ __launch_bounds__(64) void head_kernel(
    const bf16* __restrict__ xb,
    const float* __restrict__ Wp, const float* __restrict__ bp,
    const float* __restrict__ Wv, const float* __restrict__ bv,
    float* __restrict__ out)
{
    const int n    = blockIdx.x;
    const int lane = threadIdx.x;
    const bf16* row = xb + (size_t)(n*W_ + (W_-1)) * D_;
    float t[8];
#pragma unroll
    for (int j = 0; j < 8; ++j) t[j] = bf2f(*(const short*)(row + lane + j*64));

    for (int a = 0; a < A_ + 1; ++a) {
        const float* w = (a < A_) ? (Wp + (size_t)a * D_) : Wv;
        float d = 0.f;
#pragma unroll
        for (int j = 0; j < 8; ++j) d += t[j] * w[lane + j*64];
#pragma unroll
        for (int off = 32; off > 0; off >>= 1) d += __shfl_down(d, off);
        if (lane == 0) {
            if (a < A_) out[(size_t)n*A_ + a] = d + bp[a];
            else        out[(size_t)NWIN*A_ + n] = d + bv[0];
        }
    }
}

// ---------------------------------------------------------------------------
extern "C" void kernel_launch(void* const* d_in, const int* in_sizes, int n_in,
                              void* d_out, int out_size, void* d_ws, size_t ws_size,
                              hipStream_t stream) {
    const float* feats = (const float*)d_in[0];
    const float* pos   = (const float*)d_in[1];
    const float* Wqkv  = (const float*)d_in[2];
    const float* bqkv  = (const float*)d_in[3];
    const float* Wo    = (const float*)d_in[4];
    const float* bo    = (const float*)d_in[5];
    const float* ln1g  = (const float*)d_in[6];
    const float* ln1b  = (const float*)d_in[7];
    const float* W1    = (const float*)d_in[8];
    const float* b1    = (const float*)d_in[9];
    const float* W2    = (const float*)d_in[10];
    const float* b2    = (const float*)d_in[11];
    const float* ln2g  = (const float*)d_in[12];
    const float* ln2b  = (const float*)d_in[13];
    const float* Wp    = (const float*)d_in[14];
    const float* bp    = (const float*)d_in[15];
    const float* Wv    = (const float*)d_in[16];
    const float* bv    = (const float*)d_in[17];
    float* out = (float*)d_out;

    char* basep = (ws_size >= TOTAL_BYTES) ? (char*)d_ws : g_fallback;

    bf16*  xb   = (bf16*)basep;
    bf16*  wq_b = (bf16*)(basep + XB_BYTES);
    bf16*  wo_b = wq_b + WQ_ELEMS;
    bf16*  w1_b = wo_b + WO_ELEMS;
    bf16*  w2_b = w1_b + W1_ELEMS;
    bf16*  scr  = w2_b + W2_ELEMS;
    bf16*  qkv_s = scr;                            // (NTOK, 1536) attn phase
    bf16*  ctx_s = scr + (size_t)NTOK * (3*D_);    // (NTOK, 512)  attn phase
    bf16*  h_s   = scr;                            // (NTOK, 2048) FFN phase
    bf16*  y_s   = scr + (size_t)NTOK * 2048;      // (NTOK, 512)  both phases

    cvt_kernel<<<(WQ_ELEMS/4 + 255)/256, 256, 0, stream>>>(Wqkv, wq_b, WQ_ELEMS/4);
    cvt_kernel<<<(WO_ELEMS/4 + 255)/256, 256, 0, stream>>>(Wo,   wo_b, WO_ELEMS/4);
    cvt_kernel<<<(W1_ELEMS/4 + 255)/256, 256, 0, stream>>>(W1,   w1_b, W1_ELEMS/4);
    cvt_kernel<<<(W2_ELEMS/4 + 255)/256, 256, 0, stream>>>(W2,   w2_b, W2_ELEMS/4);

    build_x_kernel<<<NTOK * (D_/4) / 256, 256, 0, stream>>>(feats, pos, xb);

    const int GM = NTOK / 128;   // 512 m-blocks (div by 8, XCD remap ok)

    for (int i = 0; i < L_; ++i) {
        const bf16*  wq_i = wq_b + (size_t)i * 3*D_*D_;
        const float* bq_i = bqkv + (size_t)i * 3*D_;
        const bf16*  wo_i = wo_b + (size_t)i * D_*D_;
        const float* bo_i = bo   + (size_t)i * D_;
        const bf16*  w1_i = w1_b + (size_t)i * 4*D_*D_;
        const float* b1_i = b1   + (size_t)i * 4*D_;
        const bf16*  w2_i = w2_b + (size_t)i * 4*D_*D_;
        const float* b2_i = b2   + (size_t)i * D_;

        // qkv = xb @ Wqkv^T + bqkv
        gemm_bf16<false><<<GM * (3*D_/128), 256, 0, stream>>>(
            xb, wq_i, bq_i, qkv_s, NTOK, 3*D_, D_);
        attn_kernel<<<dim3(NWIN, H_), 256, 0, stream>>>(qkv_s, ctx_s);
        // y = ctx @ Wo^T + bo  (plain 600 TF GEMM)
        gemm_bf16<false><<<GM * (D_/128), 256, 0, stream>>>(
            ctx_s, wo_i, bo_i, y_s, NTOK, D_, D_);
        // xb = LN1(y + xb)
        lnres_kernel<<<NTOK/4, 256, 0, stream>>>(
            y_s, xb, ln1g + (size_t)i*D_, ln1b + (size_t)i*D_);
        // h = relu(xb @ W1^T + b1)
        gemm_bf16<true><<<GM * (4*D_/128), 256, 0, stream>>>(
            xb, w1_i, b1_i, h_s, NTOK, 4*D_, D_);
        // y = h @ W2^T + b2   (plain GEMM, K=2048)
        gemm_bf16<false><<<GM * (D_/128), 256, 0, stream>>>(
            h_s, w2_i, b2_i, y_s, NTOK, D_, 4*D_);
        // xb = LN2(y + xb)
        lnres_kernel<<<NTOK/4, 256, 0, stream>>>(
            y_s, xb, ln2g + (size_t)i*D_, ln2b + (size_t)i*D_);
    }

    head_kernel<<<NWIN, 64, 0, stream>>>(xb, Wp, bp, Wv, bv, out);
}

// Round 14
// 3122.251 us; speedup vs baseline: 1.3762x; 1.2231x over previous
//
#include <hip/hip_runtime.h>
#include <hip/hip_bf16.h>
#include <cstdint>
#include <cstddef>

// Problem constants (fixed by reference)
#define B_    8
#define T_    256
#define D_    512
#define W_    32
#define L_    4
#define A_    6
#define H_    8
#define DH_   64
#define NWIN  (B_*T_)            // 2048 windows
#define NTOK  (NWIN*W_)          // 65536 token rows

typedef __hip_bfloat16 bf16;
using bf16x8 = __attribute__((ext_vector_type(8))) short;  // MFMA A/B frag (4 VGPR)
using f32x4  = __attribute__((ext_vector_type(4))) float;  // MFMA C/D frag

// ---- memory plan (bytes): bf16-only residual stream ----------------------
// scr columns: attn phase qkv(1536)+ctx(512)+y(512); FFN phase h(2048)+y(512)
#define XB_BYTES  ((size_t)NTOK * D_ * 2)     // 64 MiB bf16 residual master
#define WQ_ELEMS  ((size_t)L_ * 3*D_*D_)
#define WO_ELEMS  ((size_t)L_ * D_*D_)
#define W1_ELEMS  ((size_t)L_ * 4*D_*D_)
#define W2_ELEMS  ((size_t)L_ * 4*D_*D_)
#define WB_BYTES  ((WQ_ELEMS + WO_ELEMS + W1_ELEMS + W2_ELEMS) * 2)
#define SCR_BYTES ((size_t)NTOK * 2560 * 2)   // 335 MB
#define TOTAL_BYTES (XB_BYTES + WB_BYTES + SCR_BYTES)

static char* g_fallback = nullptr;
__attribute__((constructor)) static void alloc_fallback() {
    (void)hipMalloc((void**)&g_fallback, TOTAL_BYTES);
}

// ---- async global->LDS (16B per lane; LDS dest = wave base + lane*16) -----
typedef __attribute__((address_space(3))) uint8_t* as3p;
typedef const __attribute__((address_space(1))) uint8_t* as1p;
__device__ __forceinline__ void gload_lds16(const void* g, void* l) {
    __builtin_amdgcn_global_load_lds((as1p)(const uint8_t*)g,
                                     (as3p)(uint32_t)(uintptr_t)l, 16, 0, 0);
}

__device__ __forceinline__ float bf2f(short s) {
    return __uint_as_float(((uint32_t)(uint16_t)s) << 16);
}
__device__ __forceinline__ short f2bf(float f) {
    return (short)__bfloat16_as_ushort(__float2bfloat16(f));
}

// ---------------------------------------------------------------------------
// weight convert fp32 -> bf16 (4 elems/thread)
// ---------------------------------------------------------------------------
__global__ __launch_bounds__(256) void cvt_kernel(
    const float* __restrict__ w, bf16* __restrict__ o, int n4)
{
    int i = blockIdx.x * 256 + threadIdx.x;
    if (i >= n4) return;
    float4 f = ((const float4*)w)[i];
    bf16* d = o + (size_t)i * 4;
    d[0] = __float2bfloat16(f.x);
    d[1] = __float2bfloat16(f.y);
    d[2] = __float2bfloat16(f.z);
    d[3] = __float2bfloat16(f.w);
}

// ---------------------------------------------------------------------------
// build_x: xb[n*32+w,:] = bf16(feats[b, max(t+w-31,0),:] + pos[w,:])
// ---------------------------------------------------------------------------
__global__ __launch_bounds__(256) void build_x_kernel(
    const float* __restrict__ feats,
    const float* __restrict__ pos,
    bf16* __restrict__ xb)
{
    int gid   = blockIdx.x * 256 + threadIdx.x;   // over NTOK * (D/4)
    int token = gid >> 7;
    int c4    = (gid & 127) * 4;
    int w     = token & (W_-1);
    int n     = token >> 5;
    int t     = n & (T_-1);
    int b     = n >> 8;
    int frame = t + w - (W_-1); if (frame < 0) frame = 0;
    const float4 f = *(const float4*)(feats + ((size_t)(b*T_ + frame)*D_ + c4));
    const float4 p = *(const float4*)(pos   + ((size_t)w*D_ + c4));
    bf16* d = xb + (size_t)token*D_ + c4;
    d[0] = __float2bfloat16(f.x + p.x);
    d[1] = __float2bfloat16(f.y + p.y);
    d[2] = __float2bfloat16(f.z + p.z);
    d[3] = __float2bfloat16(f.w + p.w);
}

// ---------------------------------------------------------------------------
// bf16 MFMA GEMM (BK=32, proven ~600 TF at these shapes):
// Cb = bf16(A(MxK) @ Bt(NxK)^T + bias [relu])
// 128x128 tile, 4 waves, wave 64x64 (4x4 of 16x16x32 MFMA).
// 1-D grid + XCD remap (R7: same-A-stripe blocks share one XCD L2).
// ---------------------------------------------------------------------------
template<bool RELU>
__global__ __launch_bounds__(256) void gemm_bf16(
    const bf16* __restrict__ A,
    const bf16* __restrict__ Bt,
    const float* __restrict__ bias,
    bf16* __restrict__ Cb,
    int M, int N, int K)
{
    __shared__ bf16 As[128*32];   // [row][k] row-major, 64B rows
    __shared__ bf16 Bs[128*32];

    const int tid  = threadIdx.x;
    const int lane = tid & 63;
    const int wv   = tid >> 6;

    // XCD-aware block remap (gridM % 8 == 0)
    const int gridN = N >> 7;
    const int bid   = blockIdx.x;
    const int q_    = bid >> 3;
    const int n0    = (q_ % gridN) << 7;
    const int m0    = (((q_ / gridN) * 8) + (bid & 7)) << 7;

    const int wm   = (wv >> 1) * 64;
    const int wn   = (wv & 1) * 64;

    f32x4 acc[4][4] = {};

    const int   srow  = wv*16 + (lane >> 2);
    const int   skoff = (lane & 3) * 8;
    const bf16* ga0 = A  + (size_t)(m0 + srow)      * K + skoff;
    const bf16* ga1 = A  + (size_t)(m0 + 64 + srow) * K + skoff;
    const bf16* gb0 = Bt + (size_t)(n0 + srow)      * K + skoff;
    const bf16* gb1 = Bt + (size_t)(n0 + 64 + srow) * K + skoff;
    char* lAs = (char*)As;
    char* lBs = (char*)Bs;
    const int l0 = wv*1024 + lane*16;

    const int fr = lane & 15;
    const int fq = (lane >> 4) * 16;

    for (int k0 = 0; k0 < K; k0 += 32) {
        gload_lds16(ga0 + k0, lAs + l0);
        gload_lds16(ga1 + k0, lAs + l0 + 4096);
        gload_lds16(gb0 + k0, lBs + l0);
        gload_lds16(gb1 + k0, lBs + l0 + 4096);
        __syncthreads();

        bf16x8 av[4], bv[4];
#pragma unroll
        for (int i = 0; i < 4; ++i) {
            av[i] = *(const bf16x8*)(lAs + (wm + i*16 + fr)*64 + fq);
            bv[i] = *(const bf16x8*)(lBs + (wn + i*16 + fr)*64 + fq);
        }
#pragma unroll
        for (int i = 0; i < 4; ++i)
#pragma unroll
            for (int j = 0; j < 4; ++j)
                acc[i][j] = __builtin_amdgcn_mfma_f32_16x16x32_bf16(
                    av[i], bv[j], acc[i][j], 0, 0, 0);
        __syncthreads();
    }

    // epilogue: C/D layout col=lane&15, row=(lane>>4)*4+reg
    const int er = (lane >> 4) * 4;
    const int ec = lane & 15;
#pragma unroll
    for (int i = 0; i < 4; ++i) {
#pragma unroll
        for (int j = 0; j < 4; ++j) {
            const int ncol = n0 + wn + j*16 + ec;
            const float bv_ = bias[ncol];
#pragma unroll
            for (int r = 0; r < 4; ++r) {
                const int mrow = m0 + wm + i*16 + er + r;
                float v = acc[i][j][r] + bv_;
                if (RELU) v = fmaxf(v, 0.f);
                Cb[(size_t)mrow * N + ncol] = __float2bfloat16(v);
            }
        }
    }
}

// ---------------------------------------------------------------------------
// Fused residual-add + LayerNorm (bandwidth-bound, ~192 MB/call):
//   xb = LN(y + xb) * g + b     (in place on xb; y is the GEMM output)
// ---------------------------------------------------------------------------
__global__ __launch_bounds__(256) void lnres_kernel(
    const bf16* __restrict__ y,
    bf16* xb,
    const float* __restrict__ g,
    const float* __restrict__ b)
{
    const int wave  = threadIdx.x >> 6;
    const int lane  = threadIdx.x & 63;
    const int token = blockIdx.x * 4 + wave;
    const int c0    = lane * 8;

    const bf16* yr = y  + (size_t)token * D_ + c0;
    bf16*       xr = xb + (size_t)token * D_ + c0;

    bf16x8 ty = *(const bf16x8*)yr;
    bf16x8 tx = *(const bf16x8*)xr;

    float v[8];
    float s1 = 0.f, s2 = 0.f;
#pragma unroll
    for (int j = 0; j < 8; ++j) {
        v[j] = bf2f(ty[j]) + bf2f(tx[j]);
        s1 += v[j]; s2 += v[j]*v[j];
    }
#pragma unroll
    for (int mask = 1; mask < 64; mask <<= 1) {
        s1 += __shfl_xor(s1, mask);
        s2 += __shfl_xor(s2, mask);
    }
    const float mu = s1 * (1.f / D_);
    float var = s2 * (1.f / D_) - mu * mu;
    if (var < 0.f) var = 0.f;
    const float rs = rsqrtf(var + 1e-5f);

    const float4 g0 = *(const float4*)(g + c0);
    const float4 g1 = *(const float4*)(g + c0 + 4);
    const float4 b0 = *(const float4*)(b + c0);
    const float4 b1 = *(const float4*)(b + c0 + 4);
    const float gg[8] = {g0.x,g0.y,g0.z,g0.w,g1.x,g1.y,g1.z,g1.w};
    const float bb[8] = {b0.x,b0.y,b0.z,b0.w,b1.x,b1.y,b1.z,b1.w};

    bf16x8 o;
#pragma unroll
    for (int j = 0; j < 8; ++j) {
        float t = (v[j] - mu) * rs * gg[j] + bb[j];
        o[j] = f2bf(t);
    }
    *(bf16x8*)xr = o;
}

// ---------------------------------------------------------------------------
// MFMA attention (R14) — one WAVE per (window, head). W=32, dh=64.
// S = Q K^T via 8 mfma_16x16x32 (2x2 tiles, 2 k-steps); causal softmax in
// C-layout (col=lane&15, row=quad*4+reg) with 16-lane shfl_xor row reduce;
// P -> 2 KB wave-private LDS (C-layout write, A-layout b128 read);
// ctx = P V via 8 mfma (V^T B-frags gathered early as 32 scalar b16 loads).
// Q/K A/B-frags load DIRECTLY global->VGPR in frag layout (no staging).
// No __syncthreads anywhere. 4 waves/block = 4 pairs; grid = NWIN*H/4.
// ---------------------------------------------------------------------------
__global__ __launch_bounds__(256) void attn_mfma(
    const bf16* __restrict__ qkv,   // (NTOK, 1536)
    bf16* __restrict__ ctx)         // (NTOK, 512)
{
    __shared__ short Pb[4][32*32];  // per-wave P, 2 KB each

    const int tid  = threadIdx.x;
    const int lane = tid & 63;
    const int wv   = tid >> 6;
    const int pair = blockIdx.x * 4 + wv;    // over NWIN*H
    const int win  = pair >> 3;
    const int h    = pair & 7;

    const int quad = lane >> 4;              // 0..3
    const int col  = lane & 15;              // 0..15

    const bf16* base = qkv + (size_t)win * W_ * (3*D_) + h * DH_;

    // ---- early V^T B-frags: bvv[ntd][jj] = V[quad*8+jj][ntd*16+col] ----
    bf16x8 bvv[4];
    {
        const short* vbase = (const short*)(base + 2*D_);  // V cols at +1024
#pragma unroll
        for (int ntd = 0; ntd < 4; ++ntd)
#pragma unroll
            for (int jj = 0; jj < 8; ++jj)
                bvv[ntd][jj] = vbase[(size_t)(quad*8 + jj) * (3*D_) + ntd*16 + col];
    }

    // ---- Q/K fragments direct from global (A/B layout) ----
    bf16x8 aq[2][2], bk[2][2];
#pragma unroll
    for (int mt = 0; mt < 2; ++mt)
#pragma unroll
        for (int kq = 0; kq < 2; ++kq)
            aq[mt][kq] = *(const bf16x8*)(base + (size_t)(mt*16 + col) * (3*D_)
                                          + kq*32 + quad*8);
#pragma unroll
    for (int nt = 0; nt < 2; ++nt)
#pragma unroll
        for (int kq = 0; kq < 2; ++kq)
            bk[nt][kq] = *(const bf16x8*)(base + D_ + (size_t)(nt*16 + col) * (3*D_)
                                          + kq*32 + quad*8);

    // ---- S = Q K^T ----
    f32x4 S[2][2] = {};
#pragma unroll
    for (int mt = 0; mt < 2; ++mt)
#pragma unroll
        for (int nt = 0; nt < 2; ++nt) {
            S[mt][nt] = __builtin_amdgcn_mfma_f32_16x16x32_bf16(
                aq[mt][0], bk[nt][0], S[mt][nt], 0, 0, 0);
            S[mt][nt] = __builtin_amdgcn_mfma_f32_16x16x32_bf16(
                aq[mt][1], bk[nt][1], S[mt][nt], 0, 0, 0);
        }

    // ---- causal softmax per row, write P to wave-private LDS ----
    short* P = Pb[wv];
#pragma unroll
    for (int mt = 0; mt < 2; ++mt) {
#pragma unroll
        for (int reg = 0; reg < 4; ++reg) {
            const int row = mt*16 + quad*4 + reg;
            float v0 = (col      <= row) ? S[mt][0][reg] * 0.125f : -1e30f;
            float v1 = (16 + col <= row) ? S[mt][1][reg] * 0.125f : -1e30f;
            float mx = fmaxf(v0, v1);
#pragma unroll
            for (int m = 1; m < 16; m <<= 1) mx = fmaxf(mx, __shfl_xor(mx, m));
            float e0 = __expf(v0 - mx);
            float e1 = __expf(v1 - mx);
            float sm = e0 + e1;
#pragma unroll
            for (int m = 1; m < 16; m <<= 1) sm += __shfl_xor(sm, m);
            float inv = 1.f / sm;
            P[row*32 + col]      = f2bf(e0 * inv);
            P[row*32 + 16 + col] = f2bf(e1 * inv);
        }
    }

    // ---- ctx = P V : A-frags from LDS, B-frags = bvv ----
    bf16* cb = ctx + (size_t)win * W_ * D_ + h * DH_;
#pragma unroll
    for (int mt = 0; mt < 2; ++mt) {
        bf16x8 ap = *(const bf16x8*)(P + (mt*16 + col)*32 + quad*8);
#pragma unroll
        for (int ntd = 0; ntd < 4; ++ntd) {
            f32x4 O = {};
            O = __builtin_amdgcn_mfma_f32_16x16x32_bf16(ap, bvv[ntd], O, 0, 0, 0);
#pragma unroll
            for (int reg = 0; reg < 4; ++reg) {
                const int row = mt*16 + quad*4 + reg;
                cb[(size_t)row * D_ + ntd*16 + col] = __float2bfloat16(O[reg]);
            }
        }
    }
}

// ---------------------------------------------------------------------------
// Head: token = xb[n*32+31,:] bf16; logits (NWIN,6) then values (NWIN)
// ---------------------------------------------------------------------------
__global__ __launch_bounds__(64) void head_kernel(
    const bf16* __restrict__ xb,
    const float* __restrict__ Wp, const float* __restrict__ bp,
    const float* __restrict__ Wv, const float* __restrict__ bv,
    float* __restrict__ out)
{
    const int n    = blockIdx.x;
    const int lane = threadIdx.x;
    const bf16* row = xb + (size_t)(n*W_ + (W_-1)) * D_;
    float t[8];
#pragma unroll
    for (int j = 0; j < 8; ++j) t[j] = bf2f(*(const short*)(row + lane + j*64));

    for (int a = 0; a < A_ + 1; ++a) {
        const float* w = (a < A_) ? (Wp + (size_t)a * D_) : Wv;
        float d = 0.f;
#pragma unroll
        for (int j = 0; j < 8; ++j) d += t[j] * w[lane + j*64];
#pragma unroll
        for (int off = 32; off > 0; off >>= 1) d += __shfl_down(d, off);
        if (lane == 0) {
            if (a < A_) out[(size_t)n*A_ + a] = d + bp[a];
            else        out[(size_t)NWIN*A_ + n] = d + bv[0];
        }
    }
}

// ---------------------------------------------------------------------------
extern "C" void kernel_launch(void* const* d_in, const int* in_sizes, int n_in,
                              void* d_out, int out_size, void* d_ws, size_t ws_size,
                              hipStream_t stream) {
    const float* feats = (const float*)d_in[0];
    const float* pos   = (const float*)d_in[1];
    const float* Wqkv  = (const float*)d_in[2];
    const float* bqkv  = (const float*)d_in[3];
    const float* Wo    = (const float*)d_in[4];
    const float* bo    = (const float*)d_in[5];
    const float* ln1g  = (const float*)d_in[6];
    const float* ln1b  = (const float*)d_in[7];
    const float* W1    = (const float*)d_in[8];
    const float* b1    = (const float*)d_in[9];
    const float* W2    = (const float*)d_in[10];
    const float* b2    = (const float*)d_in[11];
    const float* ln2g  = (const float*)d_in[12];
    const float* ln2b  = (const float*)d_in[13];
    const float* Wp    = (const float*)d_in[14];
    const float* bp    = (const float*)d_in[15];
    const float* Wv    = (const float*)d_in[16];
    const float* bv    = (const float*)d_in[17];
    float* out = (float*)d_out;

    char* basep = (ws_size >= TOTAL_BYTES) ? (char*)d_ws : g_fallback;

    bf16*  xb   = (bf16*)basep;
    bf16*  wq_b = (bf16*)(basep + XB_BYTES);
    bf16*  wo_b = wq_b + WQ_ELEMS;
    bf16*  w1_b = wo_b + WO_ELEMS;
    bf16*  w2_b = w1_b + W1_ELEMS;
    bf16*  scr  = w2_b + W2_ELEMS;
    bf16*  qkv_s = scr;                            // (NTOK, 1536) attn phase
    bf16*  ctx_s = scr + (size_t)NTOK * (3*D_);    // (NTOK, 512)  attn phase
    bf16*  h_s   = scr;                            // (NTOK, 2048) FFN phase
    bf16*  y_s   = scr + (size_t)NTOK * 2048;      // (NTOK, 512)  both phases

    cvt_kernel<<<(WQ_ELEMS/4 + 255)/256, 256, 0, stream>>>(Wqkv, wq_b, WQ_ELEMS/4);
    cvt_kernel<<<(WO_ELEMS/4 + 255)/256, 256, 0, stream>>>(Wo,   wo_b, WO_ELEMS/4);
    cvt_kernel<<<(W1_ELEMS/4 + 255)/256, 256, 0, stream>>>(W1,   w1_b, W1_ELEMS/4);
    cvt_kernel<<<(W2_ELEMS/4 + 255)/256, 256, 0, stream>>>(W2,   w2_b, W2_ELEMS/4);

    build_x_kernel<<<NTOK * (D_/4) / 256, 256, 0, stream>>>(feats, pos, xb);

    const int GM = NTOK / 128;   // 512 m-blocks (div by 8, XCD remap ok)

    for (int i = 0; i < L_; ++i) {
        const bf16*  wq_i = wq_b + (size_t)i * 3*D_*D_;
        const float* bq_i = bqkv + (size_t)i * 3*D_;
        const bf16*  wo_i = wo_b + (size_t)i * D_*D_;
        const float* bo_i = bo   + (size_t)i * D_;
        const bf16*  w1_i = w1_b + (size_t)i * 4*D_*D_;
        const float* b1_i = b1   + (size_t)i * 4*D_;
        const bf16*  w2_i = w2_b + (size_t)i * 4*D_*D_;
        const float* b2_i = b2   + (size_t)i * D_;

        // qkv = xb @ Wqkv^T + bqkv
        gemm_bf16<false><<<GM * (3*D_/128), 256, 0, stream>>>(
            xb, wq_i, bq_i, qkv_s, NTOK, 3*D_, D_);
        // attention (MFMA, wave per (window,head))
        attn_mfma<<<NWIN * H_ / 4, 256, 0, stream>>>(qkv_s, ctx_s);
        // y = ctx @ Wo^T + bo
        gemm_bf16<false><<<GM * (D_/128), 256, 0, stream>>>(
            ctx_s, wo_i, bo_i, y_s, NTOK, D_, D_);
        // xb = LN1(y + xb)
        lnres_kernel<<<NTOK/4, 256, 0, stream>>>(
            y_s, xb, ln1g + (size_t)i*D_, ln1b + (size_t)i*D_);
        // h = relu(xb @ W1^T + b1)
        gemm_bf16<true><<<GM * (4*D_/128), 256, 0, stream>>>(
            xb, w1_i, b1_i, h_s, NTOK, 4*D_, D_);
        // y = h @ W2^T + b2
        gemm_bf16<false><<<GM * (D_/128), 256, 0, stream>>>(
            h_s, w2_i, b2_i, y_s, NTOK, D_, 4*D_);
        // xb = LN2(y + xb)
        lnres_kernel<<<NTOK/4, 256, 0, stream>>>(
            y_s, xb, ln2g + (size_t)i*D_, ln2b + (size_t)i*D_);
    }

    head_kernel<<<NWIN, 64, 0, stream>>>(xb, Wp, bp, Wv, bv, out);
}

// Round 15
// 3001.988 us; speedup vs baseline: 1.4314x; 1.0401x over previous
//
#include <hip/hip_runtime.h>
#include <hip/hip_bf16.h>
#include <cstdint>
#include <cstddef>

// Problem constants (fixed by reference)
#define B_    8
#define T_    256
#define D_    512
#define W_    32
#define L_    4
#define A_    6
#define H_    8
#define DH_   64
#define NWIN  (B_*T_)            // 2048 windows
#define NTOK  (NWIN*W_)          // 65536 token rows
#define FROWS 2176               // layer-0 qkv factor rows: 2048 frames + 32 pos + pad

typedef __hip_bfloat16 bf16;
using bf16x8 = __attribute__((ext_vector_type(8))) short;   // MFMA A/B frag (4 VGPR)
using f32x16 = __attribute__((ext_vector_type(16))) float;  // 32x32 MFMA C/D frag

// ---- memory plan (bytes): bf16-only residual stream ----------------------
#define XB_BYTES  ((size_t)NTOK * D_ * 2)     // 64 MiB bf16 residual master
#define WQ_ELEMS  ((size_t)L_ * 3*D_*D_)
#define WO_ELEMS  ((size_t)L_ * D_*D_)
#define W1_ELEMS  ((size_t)L_ * 4*D_*D_)
#define W2_ELEMS  ((size_t)L_ * 4*D_*D_)
#define WB_BYTES  ((WQ_ELEMS + WO_ELEMS + W1_ELEMS + W2_ELEMS) * 2)
#define FB_ELEMS  ((size_t)FROWS * D_)        // layer-0 factor input
#define QF_ELEMS  ((size_t)FROWS * 3*D_)      // layer-0 factor qkv
#define SCR_BYTES ((size_t)NTOK * 2560 * 2)   // qkv+ctx+y / h+y
#define TOTAL_BYTES (XB_BYTES + WB_BYTES + (FB_ELEMS + QF_ELEMS)*2 + SCR_BYTES)

static char* g_fallback = nullptr;
__attribute__((constructor)) static void alloc_fallback() {
    (void)hipMalloc((void**)&g_fallback, TOTAL_BYTES);
}

// ---- async global->LDS (16B per lane; LDS dest = wave base + lane*16) -----
typedef __attribute__((address_space(3))) uint8_t* as3p;
typedef const __attribute__((address_space(1))) uint8_t* as1p;
__device__ __forceinline__ void gload_lds16(const void* g, void* l) {
    __builtin_amdgcn_global_load_lds((as1p)(const uint8_t*)g,
                                     (as3p)(uint32_t)(uintptr_t)l, 16, 0, 0);
}

__device__ __forceinline__ float bf2f(short s) {
    return __uint_as_float(((uint32_t)(uint16_t)s) << 16);
}
__device__ __forceinline__ short f2bf(float f) {
    return (short)__bfloat16_as_ushort(__float2bfloat16(f));
}

// ---------------------------------------------------------------------------
// weight convert fp32 -> bf16 (4 elems/thread)
// ---------------------------------------------------------------------------
__global__ __launch_bounds__(256) void cvt_kernel(
    const float* __restrict__ w, bf16* __restrict__ o, int n4)
{
    int i = blockIdx.x * 256 + threadIdx.x;
    if (i >= n4) return;
    float4 f = ((const float4*)w)[i];
    bf16* d = o + (size_t)i * 4;
    d[0] = __float2bfloat16(f.x);
    d[1] = __float2bfloat16(f.y);
    d[2] = __float2bfloat16(f.z);
    d[3] = __float2bfloat16(f.w);
}

// ---------------------------------------------------------------------------
// build_x: xb[n*32+w,:] = bf16(feats[b, max(t+w-31,0),:] + pos[w,:])
// ---------------------------------------------------------------------------
__global__ __launch_bounds__(256) void build_x_kernel(
    const float* __restrict__ feats,
    const float* __restrict__ pos,
    bf16* __restrict__ xb)
{
    int gid   = blockIdx.x * 256 + threadIdx.x;   // over NTOK * (D/4)
    int token = gid >> 7;
    int c4    = (gid & 127) * 4;
    int w     = token & (W_-1);
    int n     = token >> 5;
    int t     = n & (T_-1);
    int b     = n >> 8;
    int frame = t + w - (W_-1); if (frame < 0) frame = 0;
    const float4 f = *(const float4*)(feats + ((size_t)(b*T_ + frame)*D_ + c4));
    const float4 p = *(const float4*)(pos   + ((size_t)w*D_ + c4));
    bf16* d = xb + (size_t)token*D_ + c4;
    d[0] = __float2bfloat16(f.x + p.x);
    d[1] = __float2bfloat16(f.y + p.y);
    d[2] = __float2bfloat16(f.z + p.z);
    d[3] = __float2bfloat16(f.w + p.w);
}

// ---------------------------------------------------------------------------
// build_fb (R15): factor matrix for layer-0 qkv.
// rows 0..2047 = bf16(feats frames); rows 2048..2079 = bf16(pos); pad = 0.
// ---------------------------------------------------------------------------
__global__ __launch_bounds__(256) void build_fb_kernel(
    const float* __restrict__ feats,
    const float* __restrict__ pos,
    bf16* __restrict__ fb)
{
    int gid = blockIdx.x * 256 + threadIdx.x;     // over FROWS * (D/4)
    int row = gid >> 7;
    int c4  = (gid & 127) * 4;
    bf16* d = fb + (size_t)row * D_ + c4;
    float4 f;
    if (row < 2048)      f = *(const float4*)(feats + (size_t)row * D_ + c4);
    else if (row < 2080) f = *(const float4*)(pos + (size_t)(row - 2048) * D_ + c4);
    else                 f = make_float4(0.f, 0.f, 0.f, 0.f);
    d[0] = __float2bfloat16(f.x);
    d[1] = __float2bfloat16(f.y);
    d[2] = __float2bfloat16(f.z);
    d[3] = __float2bfloat16(f.w);
}

// ---------------------------------------------------------------------------
// qkv_gather (R15): layer-0 qkv from factors (qf L3-resident, 6.7 MB):
//   qkv[n*32+w, c] = qf[frame(n,w), c] + qf[2048+w, c] + bqkv[c]
// ---------------------------------------------------------------------------
__global__ __launch_bounds__(256) void qkv_gather_kernel(
    const bf16* __restrict__ qf,
    const float* __restrict__ bq,
    bf16* __restrict__ qkv)
{
    int gid   = blockIdx.x * 256 + threadIdx.x;   // over NTOK * (3D/8)
    int token = gid / 192;
    int c0    = (gid % 192) * 8;
    int w     = token & (W_-1);
    int n     = token >> 5;
    int t     = n & (T_-1);
    int b     = n >> 8;
    int frame = t + w - (W_-1); if (frame < 0) frame = 0;
    const bf16x8 a = *(const bf16x8*)(qf + (size_t)(b*T_ + frame) * (3*D_) + c0);
    const bf16x8 p = *(const bf16x8*)(qf + (size_t)(2048 + w)     * (3*D_) + c0);
    bf16x8 o;
#pragma unroll
    for (int j = 0; j < 8; ++j)
        o[j] = f2bf(bf2f(a[j]) + bf2f(p[j]) + bq[c0 + j]);
    *(bf16x8*)(qkv + (size_t)token * (3*D_) + c0) = o;
}

// ---------------------------------------------------------------------------
// bf16 MFMA GEMM — R15: 32x32x16 MFMA (8 instr/K-step vs 16; m119: 2495 TF
// pipe rate vs 2176). Cb = bf16(A(MxK) @ Bt(NxK)^T [+ bias] [relu]).
// 128x128 tile, BK=32, 4 waves, wave 64x64 = 2x2 of 32x32 tiles.
// A/B frag: [rc=lane&31][k=(lane>>5)*8+j]; C/D: col=lane&31,
// row=(reg&3)+8*(reg>>2)+4*(lane>>5)  [m74/m101-verified].
// REMAP: XCD-aware 1-D remap (requires gridM%8==0); else plain n-major.
// ---------------------------------------------------------------------------
template<bool RELU, bool BIAS, bool REMAP>
__global__ __launch_bounds__(256) void gemm_bf16(
    const bf16* __restrict__ A,
    const bf16* __restrict__ Bt,
    const float* __restrict__ bias,
    bf16* __restrict__ Cb,
    int M, int N, int K)
{
    __shared__ bf16 As[128*32];   // [row][k] row-major, 64B rows
    __shared__ bf16 Bs[128*32];

    const int tid  = threadIdx.x;
    const int lane = tid & 63;
    const int wv   = tid >> 6;

    const int gridN = N >> 7;
    const int bid   = blockIdx.x;
    int m0, n0;
    if (REMAP) {
        const int q_ = bid >> 3;
        n0 = (q_ % gridN) << 7;
        m0 = (((q_ / gridN) * 8) + (bid & 7)) << 7;
    } else {
        n0 = (bid % gridN) << 7;
        m0 = (bid / gridN) << 7;
    }

    const int wm = (wv >> 1) * 64;
    const int wn = (wv & 1) * 64;

    f32x16 acc[2][2] = {};

    const int   srow  = wv*16 + (lane >> 2);
    const int   skoff = (lane & 3) * 8;
    const bf16* ga0 = A  + (size_t)(m0 + srow)      * K + skoff;
    const bf16* ga1 = A  + (size_t)(m0 + 64 + srow) * K + skoff;
    const bf16* gb0 = Bt + (size_t)(n0 + srow)      * K + skoff;
    const bf16* gb1 = Bt + (size_t)(n0 + 64 + srow) * K + skoff;
    char* lAs = (char*)As;
    char* lBs = (char*)Bs;
    const int l0 = wv*1024 + lane*16;

    const int r32  = lane & 31;
    const int ksel = (lane >> 5) * 16;   // byte offset of k-subgroup in 32B half

    for (int k0 = 0; k0 < K; k0 += 32) {
        gload_lds16(ga0 + k0, lAs + l0);
        gload_lds16(ga1 + k0, lAs + l0 + 4096);
        gload_lds16(gb0 + k0, lBs + l0);
        gload_lds16(gb1 + k0, lBs + l0 + 4096);
        __syncthreads();

        bf16x8 av[2][2], bv[2][2];
#pragma unroll
        for (int i = 0; i < 2; ++i)
#pragma unroll
            for (int h = 0; h < 2; ++h) {
                av[i][h] = *(const bf16x8*)(lAs + (wm + i*32 + r32)*64 + h*32 + ksel);
                bv[i][h] = *(const bf16x8*)(lBs + (wn + i*32 + r32)*64 + h*32 + ksel);
            }
#pragma unroll
        for (int i = 0; i < 2; ++i)
#pragma unroll
            for (int j = 0; j < 2; ++j) {
                acc[i][j] = __builtin_amdgcn_mfma_f32_32x32x16_bf16(
                    av[i][0], bv[j][0], acc[i][j], 0, 0, 0);
                acc[i][j] = __builtin_amdgcn_mfma_f32_32x32x16_bf16(
                    av[i][1], bv[j][1], acc[i][j], 0, 0, 0);
            }
        __syncthreads();
    }

    // epilogue: 32x32 C/D layout
    const int rbase = (lane >> 5) * 4;
#pragma unroll
    for (int i = 0; i < 2; ++i) {
#pragma unroll
        for (int j = 0; j < 2; ++j) {
            const int ncol = n0 + wn + j*32 + r32;
            const float bv_ = BIAS ? bias[ncol] : 0.f;
#pragma unroll
            for (int reg = 0; reg < 16; ++reg) {
                const int mrow = m0 + wm + i*32 + (reg & 3) + 8*(reg >> 2) + rbase;
                float v = acc[i][j][reg] + bv_;
                if (RELU) v = fmaxf(v, 0.f);
                Cb[(size_t)mrow * N + ncol] = __float2bfloat16(v);
            }
        }
    }
}

// ---------------------------------------------------------------------------
// Fused residual-add + LayerNorm (bandwidth-bound):
//   xb = LN(y + xb) * g + b
// ---------------------------------------------------------------------------
__global__ __launch_bounds__(256) void lnres_kernel(
    const bf16* __restrict__ y,
    bf16* xb,
    const float* __restrict__ g,
    const float* __restrict__ b)
{
    const int wave  = threadIdx.x >> 6;
    const int lane  = threadIdx.x & 63;
    const int token = blockIdx.x * 4 + wave;
    const int c0    = lane * 8;

    const bf16* yr = y  + (size_t)token * D_ + c0;
    bf16*       xr = xb + (size_t)token * D_ + c0;

    bf16x8 ty = *(const bf16x8*)yr;
    bf16x8 tx = *(const bf16x8*)xr;

    float v[8];
    float s1 = 0.f, s2 = 0.f;
#pragma unroll
    for (int j = 0; j < 8; ++j) {
        v[j] = bf2f(ty[j]) + bf2f(tx[j]);
        s1 += v[j]; s2 += v[j]*v[j];
    }
#pragma unroll
    for (int mask = 1; mask < 64; mask <<= 1) {
        s1 += __shfl_xor(s1, mask);
        s2 += __shfl_xor(s2, mask);
    }
    const float mu = s1 * (1.f / D_);
    float var = s2 * (1.f / D_) - mu * mu;
    if (var < 0.f) var = 0.f;
    const float rs = rsqrtf(var + 1e-5f);

    const float4 g0 = *(const float4*)(g + c0);
    const float4 g1 = *(const float4*)(g + c0 + 4);
    const float4 b0 = *(const float4*)(b + c0);
    const float4 b1 = *(const float4*)(b + c0 + 4);
    const float gg[8] = {g0.x,g0.y,g0.z,g0.w,g1.x,g1.y,g1.z,g1.w};
    const float bb[8] = {b0.x,b0.y,b0.z,b0.w,b1.x,b1.y,b1.z,b1.w};

    bf16x8 o;
#pragma unroll
    for (int j = 0; j < 8; ++j) {
        float t = (v[j] - mu) * rs * gg[j] + bb[j];
        o[j] = f2bf(t);
    }
    *(bf16x8*)xr = o;
}

// ---------------------------------------------------------------------------
// MFMA attention — one WAVE per (window, head). W=32, dh=64. (R14, verified)
// ---------------------------------------------------------------------------
__global__ __launch_bounds__(256) void attn_mfma(
    const bf16* __restrict__ qkv,   // (NTOK, 1536)
    bf16* __restrict__ ctx)         // (NTOK, 512)
{
    __shared__ short Pb[4][32*32];  // per-wave P, 2 KB each

    const int tid  = threadIdx.x;
    const int lane = tid & 63;
    const int wv   = tid >> 6;
    const int pair = blockIdx.x * 4 + wv;    // over NWIN*H
    const int win  = pair >> 3;
    const int h    = pair & 7;

    const int quad = lane >> 4;              // 0..3
    const int col  = lane & 15;              // 0..15

    const bf16* base = qkv + (size_t)win * W_ * (3*D_) + h * DH_;

    // early V^T B-frags: bvv[ntd][jj] = V[quad*8+jj][ntd*16+col]
    bf16x8 bvv[4];
    {
        const short* vbase = (const short*)(base + 2*D_);
#pragma unroll
        for (int ntd = 0; ntd < 4; ++ntd)
#pragma unroll
            for (int jj = 0; jj < 8; ++jj)
                bvv[ntd][jj] = vbase[(size_t)(quad*8 + jj) * (3*D_) + ntd*16 + col];
    }

    // Q/K fragments direct from global (A/B layout)
    bf16x8 aq[2][2], bk[2][2];
#pragma unroll
    for (int mt = 0; mt < 2; ++mt)
#pragma unroll
        for (int kq = 0; kq < 2; ++kq)
            aq[mt][kq] = *(const bf16x8*)(base + (size_t)(mt*16 + col) * (3*D_)
                                          + kq*32 + quad*8);
#pragma unroll
    for (int nt = 0; nt < 2; ++nt)
#pragma unroll
        for (int kq = 0; kq < 2; ++kq)
            bk[nt][kq] = *(const bf16x8*)(base + D_ + (size_t)(nt*16 + col) * (3*D_)
                                          + kq*32 + quad*8);

    // S = Q K^T
    using f32x4 = __attribute__((ext_vector_type(4))) float;
    f32x4 S[2][2] = {};
#pragma unroll
    for (int mt = 0; mt < 2; ++mt)
#pragma unroll
        for (int nt = 0; nt < 2; ++nt) {
            S[mt][nt] = __builtin_amdgcn_mfma_f32_16x16x32_bf16(
                aq[mt][0], bk[nt][0], S[mt][nt], 0, 0, 0);
            S[mt][nt] = __builtin_amdgcn_mfma_f32_16x16x32_bf16(
                aq[mt][1], bk[nt][1], S[mt][nt], 0, 0, 0);
        }

    // causal softmax per row, write P to wave-private LDS
    short* P = Pb[wv];
#pragma unroll
    for (int mt = 0; mt < 2; ++mt) {
#pragma unroll
        for (int reg = 0; reg < 4; ++reg) {
            const int row = mt*16 + quad*4 + reg;
            float v0 = (col      <= row) ? S[mt][0][reg] * 0.125f : -1e30f;
            float v1 = (16 + col <= row) ? S[mt][1][reg] * 0.125f : -1e30f;
            float mx = fmaxf(v0, v1);
#pragma unroll
            for (int m = 1; m < 16; m <<= 1) mx = fmaxf(mx, __shfl_xor(mx, m));
            float e0 = __expf(v0 - mx);
            float e1 = __expf(v1 - mx);
            float sm = e0 + e1;
#pragma unroll
            for (int m = 1; m < 16; m <<= 1) sm += __shfl_xor(sm, m);
            float inv = 1.f / sm;
            P[row*32 + col]      = f2bf(e0 * inv);
            P[row*32 + 16 + col] = f2bf(e1 * inv);
        }
    }

    // ctx = P V
    bf16* cb = ctx + (size_t)win * W_ * D_ + h * DH_;
#pragma unroll
    for (int mt = 0; mt < 2; ++mt) {
        bf16x8 ap = *(const bf16x8*)(P + (mt*16 + col)*32 + quad*8);
#pragma unroll
        for (int ntd = 0; ntd < 4; ++ntd) {
            f32x4 O = {};
            O = __builtin_amdgcn_mfma_f32_16x16x32_bf16(ap, bvv[ntd], O, 0, 0, 0);
#pragma unroll
            for (int reg = 0; reg < 4; ++reg) {
                const int row = mt*16 + quad*4 + reg;
                cb[(size_t)row * D_ + ntd*16 + col] = __float2bfloat16(O[reg]);
            }
        }
    }
}

// ---------------------------------------------------------------------------
// Head: token = xb[n*32+31,:] bf16; logits (NWIN,6) then values (NWIN)
// ---------------------------------------------------------------------------
__global__ __launch_bounds__(64) void head_kernel(
    const bf16* __restrict__ xb,
    const float* __restrict__ Wp, const float* __restrict__ bp,
    const float* __restrict__ Wv, const float* __restrict__ bv,
    float* __restrict__ out)
{
    const int n    = blockIdx.x;
    const int lane = threadIdx.x;
    const bf16* row = xb + (size_t)(n*W_ + (W_-1)) * D_;
    float t[8];
#pragma unroll
    for (int j = 0; j < 8; ++j) t[j] = bf2f(*(const short*)(row + lane + j*64));

    for (int a = 0; a < A_ + 1; ++a) {
        const float* w = (a < A_) ? (Wp + (size_t)a * D_) : Wv;
        float d = 0.f;
#pragma unroll
        for (int j = 0; j < 8; ++j) d += t[j] * w[lane + j*64];
#pragma unroll
        for (int off = 32; off > 0; off >>= 1) d += __shfl_down(d, off);
        if (lane == 0) {
            if (a < A_) out[(size_t)n*A_ + a] = d + bp[a];
            else        out[(size_t)NWIN*A_ + n] = d + bv[0];
        }
    }
}

// ---------------------------------------------------------------------------
extern "C" void kernel_launch(void* const* d_in, const int* in_sizes, int n_in,
                              void* d_out, int out_size, void* d_ws, size_t ws_size,
                              hipStream_t stream) {
    const float* feats = (const float*)d_in[0];
    const float* pos   = (const float*)d_in[1];
    const float* Wqkv  = (const float*)d_in[2];
    const float* bqkv  = (const float*)d_in[3];
    const float* Wo    = (const float*)d_in[4];
    const float* bo    = (const float*)d_in[5];
    const float* ln1g  = (const float*)d_in[6];
    const float* ln1b  = (const float*)d_in[7];
    const float* W1    = (const float*)d_in[8];
    const float* b1    = (const float*)d_in[9];
    const float* W2    = (const float*)d_in[10];
    const float* b2    = (const float*)d_in[11];
    const float* ln2g  = (const float*)d_in[12];
    const float* ln2b  = (const float*)d_in[13];
    const float* Wp    = (const float*)d_in[14];
    const float* bp    = (const float*)d_in[15];
    const float* Wv    = (const float*)d_in[16];
    const float* bv    = (const float*)d_in[17];
    float* out = (float*)d_out;

    char* basep = (ws_size >= TOTAL_BYTES) ? (char*)d_ws : g_fallback;

    bf16*  xb   = (bf16*)basep;
    bf16*  wq_b = (bf16*)(basep + XB_BYTES);
    bf16*  wo_b = wq_b + WQ_ELEMS;
    bf16*  w1_b = wo_b + WO_ELEMS;
    bf16*  w2_b = w1_b + W1_ELEMS;
    bf16*  fb   = w2_b + W2_ELEMS;                 // (FROWS, 512)
    bf16*  qf   = fb + FB_ELEMS;                   // (FROWS, 1536)
    bf16*  scr  = qf + QF_ELEMS;
    bf16*  qkv_s = scr;                            // (NTOK, 1536) attn phase
    bf16*  ctx_s = scr + (size_t)NTOK * (3*D_);    // (NTOK, 512)  attn phase
    bf16*  h_s   = scr;                            // (NTOK, 2048) FFN phase
    bf16*  y_s   = scr + (size_t)NTOK * 2048;      // (NTOK, 512)  both phases

    cvt_kernel<<<(WQ_ELEMS/4 + 255)/256, 256, 0, stream>>>(Wqkv, wq_b, WQ_ELEMS/4);
    cvt_kernel<<<(WO_ELEMS/4 + 255)/256, 256, 0, stream>>>(Wo,   wo_b, WO_ELEMS/4);
    cvt_kernel<<<(W1_ELEMS/4 + 255)/256, 256, 0, stream>>>(W1,   w1_b, W1_ELEMS/4);
    cvt_kernel<<<(W2_ELEMS/4 + 255)/256, 256, 0, stream>>>(W2,   w2_b, W2_ELEMS/4);

    build_x_kernel<<<NTOK * (D_/4) / 256, 256, 0, stream>>>(feats, pos, xb);
    build_fb_kernel<<<FROWS * (D_/4) / 256, 256, 0, stream>>>(feats, pos, fb);

    const int GM = NTOK / 128;   // 512 m-blocks (div by 8, XCD remap ok)

    for (int i = 0; i < L_; ++i) {
        const bf16*  wq_i = wq_b + (size_t)i * 3*D_*D_;
        const float* bq_i = bqkv + (size_t)i * 3*D_;
        const bf16*  wo_i = wo_b + (size_t)i * D_*D_;
        const float* bo_i = bo   + (size_t)i * D_;
        const bf16*  w1_i = w1_b + (size_t)i * 4*D_*D_;
        const float* b1_i = b1   + (size_t)i * 4*D_;
        const bf16*  w2_i = w2_b + (size_t)i * 4*D_*D_;
        const float* b2_i = b2   + (size_t)i * D_;

        if (i == 0) {
            // layer-0 qkv via factors: qf = fb @ Wqkv^T (2176 rows only),
            // then gather-add (frame + pos + bias). Saves the 65536-row GEMM.
            gemm_bf16<false,false,false><<<(FROWS/128) * (3*D_/128), 256, 0, stream>>>(
                fb, wq_i, nullptr, qf, FROWS, 3*D_, D_);
            qkv_gather_kernel<<<NTOK * 192 / 256, 256, 0, stream>>>(qf, bq_i, qkv_s);
        } else {
            gemm_bf16<false,true,true><<<GM * (3*D_/128), 256, 0, stream>>>(
                xb, wq_i, bq_i, qkv_s, NTOK, 3*D_, D_);
        }
        attn_mfma<<<NWIN * H_ / 4, 256, 0, stream>>>(qkv_s, ctx_s);
        // y = ctx @ Wo^T + bo
        gemm_bf16<false,true,true><<<GM * (D_/128), 256, 0, stream>>>(
            ctx_s, wo_i, bo_i, y_s, NTOK, D_, D_);
        // xb = LN1(y + xb)
        lnres_kernel<<<NTOK/4, 256, 0, stream>>>(
            y_s, xb, ln1g + (size_t)i*D_, ln1b + (size_t)i*D_);
        // h = relu(xb @ W1^T + b1)
        gemm_bf16<true,true,true><<<GM * (4*D_/128), 256, 0, stream>>>(
            xb, w1_i, b1_i, h_s, NTOK, 4*D_, D_);
        // y = h @ W2^T + b2
        gemm_bf16<false,true,true><<<GM * (D_/128), 256, 0, stream>>>(
            h_s, w2_i, b2_i, y_s, NTOK, D_, 4*D_);
        // xb = LN2(y + xb)
        lnres_kernel<<<NTOK/4, 256, 0, stream>>>(
            y_s, xb, ln2g + (size_t)i*D_, ln2b + (size_t)i*D_);
    }

    head_kernel<<<NWIN, 64, 0, stream>>>(xb, Wp, bp, Wv, bv, out);
}